// Round 2
// baseline (1476.185 us; speedup 1.0000x reference)
//
#include <hip/hip_runtime.h>
#include <hip/hip_bf16.h>
#include <math.h>

#define MM 4096
#define KK 768
#define PADI(m) ((m) + ((m) >> 4))

// ---------------- normalize rows ----------------
__global__ __launch_bounds__(256) void knorm(const float* __restrict__ emb,
                                             float* __restrict__ normed) {
  int row = blockIdx.x;
  int tid = threadIdx.x;
  const float* e = emb + (size_t)row * KK;
  float v0 = e[tid], v1 = e[tid + 256], v2 = e[tid + 512];
  float ss = v0 * v0 + v1 * v1 + v2 * v2;
  for (int s = 32; s; s >>= 1) ss += __shfl_down(ss, s, 64);
  __shared__ float red[4];
  if ((tid & 63) == 0) red[tid >> 6] = ss;
  __syncthreads();
  float tot = red[0] + red[1] + red[2] + red[3];
  float inv = 1.f / fmaxf(sqrtf(tot), 1e-12f);
  float* o = normed + (size_t)row * KK;
  o[tid] = v0 * inv;
  o[tid + 256] = v1 * inv;
  o[tid + 512] = v2 * inv;
}

// ---------------- rank-sort labels per dim ----------------
__global__ __launch_bounds__(256) void ksort(const float* __restrict__ labels,
                                             float* __restrict__ slab,
                                             int* __restrict__ perm,
                                             int* __restrict__ pos) {
  __shared__ float lab[MM];
  int d = blockIdx.x >> 4;
  int slice = blockIdx.x & 15;
  for (int i = threadIdx.x; i < MM; i += 256) lab[i] = labels[(size_t)i * 2 + d];
  __syncthreads();
  int i = slice * 256 + threadIdx.x;
  float v = lab[i];
  int r = 0;
  for (int k = 0; k < MM; ++k) {
    float w = lab[k];
    r += (w < v) || (w == v && k < i);
  }
  slab[d * MM + r] = v;
  perm[d * MM + r] = i;
  pos[d * MM + i] = r;
}

// ---------------- fp32 GEMM: exp_sims chunk = exp(10 * A·A^T) ----------------
__global__ __launch_bounds__(256) void kgemm(const float* __restrict__ A,
                                             int rowBase,
                                             float* __restrict__ out) {
  __shared__ __align__(16) float As[16 * 128];
  __shared__ __align__(16) float Bs[16 * 128];
  int tid = threadIdx.x;
  int col0 = blockIdx.x * 128;
  int row0 = rowBase + blockIdx.y * 128;
  int tr = tid >> 4, tc = tid & 15;

  float acc[8][8];
#pragma unroll
  for (int u = 0; u < 8; ++u)
#pragma unroll
    for (int v = 0; v < 8; ++v) acc[u][v] = 0.f;

  for (int k0 = 0; k0 < KK; k0 += 16) {
    __syncthreads();
#pragma unroll
    for (int q = 0; q < 2; ++q) {
      int l = tid + 256 * q;
      int r = l >> 2, seg = l & 3;
      float4 va = *(const float4*)(A + (size_t)(row0 + r) * KK + k0 + seg * 4);
      As[(seg * 4 + 0) * 128 + r] = va.x;
      As[(seg * 4 + 1) * 128 + r] = va.y;
      As[(seg * 4 + 2) * 128 + r] = va.z;
      As[(seg * 4 + 3) * 128 + r] = va.w;
      float4 vb = *(const float4*)(A + (size_t)(col0 + r) * KK + k0 + seg * 4);
      Bs[(seg * 4 + 0) * 128 + r] = vb.x;
      Bs[(seg * 4 + 1) * 128 + r] = vb.y;
      Bs[(seg * 4 + 2) * 128 + r] = vb.z;
      Bs[(seg * 4 + 3) * 128 + r] = vb.w;
    }
    __syncthreads();
#pragma unroll
    for (int kk = 0; kk < 16; ++kk) {
      float a[8], b[8];
      *(float4*)(a) = *(float4*)&As[kk * 128 + tr * 8];
      *(float4*)(a + 4) = *(float4*)&As[kk * 128 + tr * 8 + 4];
      *(float4*)(b) = *(float4*)&Bs[kk * 128 + tc * 8];
      *(float4*)(b + 4) = *(float4*)&Bs[kk * 128 + tc * 8 + 4];
#pragma unroll
      for (int u = 0; u < 8; ++u)
#pragma unroll
        for (int v = 0; v < 8; ++v) acc[u][v] = fmaf(a[u], b[v], acc[u][v]);
    }
  }

  int rloc0 = (row0 - rowBase) + tr * 8;
#pragma unroll
  for (int u = 0; u < 8; ++u) {
    float4 o1, o2;
    o1.x = expf(acc[u][0] * 10.f);
    o1.y = expf(acc[u][1] * 10.f);
    o1.z = expf(acc[u][2] * 10.f);
    o1.w = expf(acc[u][3] * 10.f);
    o2.x = expf(acc[u][4] * 10.f);
    o2.y = expf(acc[u][5] * 10.f);
    o2.z = expf(acc[u][6] * 10.f);
    o2.w = expf(acc[u][7] * 10.f);
    float* p = out + (size_t)(rloc0 + u) * MM + col0 + tc * 8;
    *(float4*)(p) = o1;
    *(float4*)(p + 4) = o2;
  }
}

// ---------------- per-row loss: sorted-order sweep with two-pointer ----------------
__global__ __launch_bounds__(256) void kloss(const float* __restrict__ expchunk,
                                             int rowBase,
                                             const float* __restrict__ slab_g,
                                             const int* __restrict__ perm_g,
                                             const int* __restrict__ pos_g,
                                             float* __restrict__ part_logd,
                                             float* __restrict__ part_sims) {
  const int i = rowBase + blockIdx.x;
  const float* row = expchunk + (size_t)blockIdx.x * MM;
  __shared__ float E_[PADI(MM) + 1];
  __shared__ float S_[PADI(MM) + 1];
  __shared__ float slab[MM];
  __shared__ float sc[256];
  __shared__ float rs[256];
  __shared__ float red[4];
  int tid = threadIdx.x;
  int m0 = tid * 16;

  float simsum = 0.f;  // sum_{j != i} sims[i][j], accumulated during d == 0

  for (int d = 0; d < 2; ++d) {
    __syncthreads();  // protect slab/E_/S_/red from previous-phase readers
    for (int m = tid; m < MM; m += 256) slab[m] = slab_g[d * MM + m];

    const int pi = pos_g[d * MM + i];

    // gather exp_sims into sorted order; per-thread contiguous chunk of 16
    float g[16];
    int idx[16];
    {
      const int4* pm4 = (const int4*)(perm_g + d * MM + m0);
#pragma unroll
      for (int q = 0; q < 4; ++q) {
        int4 p4 = pm4[q];
        idx[4 * q + 0] = p4.x; idx[4 * q + 1] = p4.y;
        idx[4 * q + 2] = p4.z; idx[4 * q + 3] = p4.w;
      }
    }
    float ls = 0.f;
#pragma unroll
    for (int u = 0; u < 16; ++u) {
      g[u] = row[idx[u]];
      ls += g[u];
    }
    if (d == 0) {
#pragma unroll
      for (int u = 0; u < 16; ++u)
        simsum += (m0 + u == pi) ? 0.f : logf(g[u]);
    }
    sc[tid] = ls;
    rs[tid] = ls;
    __syncthreads();
    // forward + reverse inclusive Hillis-Steele scans over per-thread sums
    for (int s = 1; s < 256; s <<= 1) {
      float va = (tid >= s) ? sc[tid - s] : 0.f;
      float vb = (tid + s < 256) ? rs[tid + s] : 0.f;
      __syncthreads();
      sc[tid] += va;
      rs[tid] += vb;
      __syncthreads();
    }
    float total = sc[255];
    float eoff = (tid > 0) ? sc[tid - 1] : 0.f;
    float soff = (tid < 255) ? rs[tid + 1] : 0.f;
    float run = eoff;
#pragma unroll
    for (int u = 0; u < 16; ++u) {
      E_[PADI(m0 + u)] = run;
      run += g[u];
    }
    float run2 = soff;
#pragma unroll
    for (int u = 15; u >= 0; --u) {
      run2 += g[u];
      S_[PADI(m0 + u)] = run2;
    }
    if (tid == 0) {
      E_[PADI(MM)] = total;
      S_[PADI(MM)] = 0.f;
    }
    __syncthreads();

    const float c = slab[pi];

    // chunk's sorted-label values (vector LDS read)
    float sm[16];
#pragma unroll
    for (int q = 0; q < 4; ++q)
      *(float4*)(sm + 4 * q) = *(const float4*)&slab[m0 + 4 * q];

    // init far pointers: one binary search per side actually present in chunk
    int loL = pi, hiR = pi;
    {
      int firstR = (m0 + 15 > pi) ? (m0 > pi ? m0 : pi + 1) : -1;
      if (firstR >= 0) {
        float t = slab[firstR] - c;  // == |slab[firstR]-c| exactly
        int a = 0, b = pi;
        while (a < b) {
          int mid = (a + b) >> 1;
          if (c - slab[mid] < t) b = mid; else a = mid + 1;
        }
        loL = a;
      }
      int firstL = (m0 < pi) ? m0 : -1;
      if (firstL >= 0) {
        float t = c - slab[firstL];
        int a = pi, b = MM;
        while (a < b) {
          int mid = (a + b) >> 1;
          if (slab[mid] - c >= t) b = mid; else a = mid + 1;
        }
        hiR = a;
      }
    }

    float acc = 0.f;
#pragma unroll 4
    for (int u = 0; u < 16; ++u) {
      int m = m0 + u;
      if (m == pi) continue;
      float t = fabsf(sm[u] - c);
      float denom;
      if (t == 0.f) {
        denom = total;  // all dists >= 0
      } else if (m > pi) {
        // near boundary: hi = first idx >= pi with dist >= t; ties walk-back from m
        int hi = m;
        while (hi > pi + 1 && slab[hi - 1] - c >= t) --hi;
        // far boundary: loL = first idx in [0,pi] with dist < t (t grows -> loL shrinks)
        while (loL > 0 && c - slab[loL - 1] < t) --loL;
        while (loL < pi && c - slab[loL] >= t) ++loL;
        denom = E_[PADI(loL)] + S_[PADI(hi)];
      } else {
        // near boundary: lo = first idx with dist < t; ties walk-forward from m+1
        int lo = m + 1;
        while (lo < pi && c - slab[lo] >= t) ++lo;
        // far boundary: hiR = first idx >= pi with dist >= t (t shrinks -> hiR shrinks)
        while (hiR > pi && slab[hiR - 1] - c >= t) --hiR;
        while (hiR < MM && slab[hiR] - c < t) ++hiR;
        denom = E_[PADI(lo)] + S_[PADI(hiR)];
      }
      acc += logf(fmaxf(denom, 1e-7f));
    }
    for (int s = 32; s; s >>= 1) acc += __shfl_down(acc, s, 64);
    __syncthreads();
    if ((tid & 63) == 0) red[tid >> 6] = acc;
    __syncthreads();
    if (tid == 0) part_logd[d * MM + i] = red[0] + red[1] + red[2] + red[3];
  }

  // reduce simsum
  for (int s = 32; s; s >>= 1) simsum += __shfl_down(simsum, s, 64);
  __syncthreads();
  if ((tid & 63) == 0) red[tid >> 6] = simsum;
  __syncthreads();
  if (tid == 0) part_sims[i] = red[0] + red[1] + red[2] + red[3];
}

// ---------------- final reduce (double) ----------------
__global__ __launch_bounds__(256) void kreduce(const float* __restrict__ part_logd,
                                               const float* __restrict__ part_sims,
                                               float* __restrict__ out) {
  int tid = threadIdx.x;
  double s0 = 0.0, s1 = 0.0, ss = 0.0;
  for (int i = tid; i < MM; i += 256) {
    s0 += (double)part_logd[i];
    s1 += (double)part_logd[MM + i];
    ss += (double)part_sims[i];
  }
  for (int s = 32; s; s >>= 1) {
    s0 += __shfl_down(s0, s, 64);
    s1 += __shfl_down(s1, s, 64);
    ss += __shfl_down(ss, s, 64);
  }
  __shared__ double red[3][4];
  if ((tid & 63) == 0) {
    red[0][tid >> 6] = s0;
    red[1][tid >> 6] = s1;
    red[2][tid >> 6] = ss;
  }
  __syncthreads();
  if (tid == 0) {
    double t0 = red[0][0] + red[0][1] + red[0][2] + red[0][3];
    double t1 = red[1][0] + red[1][1] + red[1][2] + red[1][3];
    double ts = red[2][0] + red[2][1] + red[2][2] + red[2][3];
    double n = (double)MM * (double)(MM - 1);
    out[0] = (float)((t0 - ts) / n);
    out[1] = (float)((t1 - ts) / n);
  }
}

extern "C" void kernel_launch(void* const* d_in, const int* in_sizes, int n_in,
                              void* d_out, int out_size, void* d_ws, size_t ws_size,
                              hipStream_t stream) {
  const float* emb = (const float*)d_in[0];
  const float* labels = (const float*)d_in[1];
  float* out = (float*)d_out;
  char* ws = (char*)d_ws;

  size_t off = 0;
  auto alloc = [&](size_t bytes) {
    void* p = ws + off;
    off = (off + bytes + 255) & ~(size_t)255;
    return p;
  };
  float* normed = (float*)alloc((size_t)MM * KK * 4);
  float* slab = (float*)alloc((size_t)2 * MM * 4);
  int* perm = (int*)alloc((size_t)2 * MM * 4);
  int* pos = (int*)alloc((size_t)2 * MM * 4);
  float* part_logd = (float*)alloc((size_t)2 * MM * 4);
  float* part_sims = (float*)alloc((size_t)MM * 4);
  size_t fixed = off;

  size_t avail = (ws_size > fixed) ? (ws_size - fixed) : 0;
  long long cr = (long long)(avail / ((size_t)MM * 4));
  cr = (cr / 128) * 128;
  if (cr > MM) cr = MM;
  if (cr < 128) cr = 128;
  int chunk_rows = (int)cr;
  float* expchunk = (float*)(ws + fixed);

  knorm<<<MM, 256, 0, stream>>>(emb, normed);
  ksort<<<32, 256, 0, stream>>>(labels, slab, perm, pos);

  for (int base = 0; base < MM; base += chunk_rows) {
    int rows = MM - base < chunk_rows ? MM - base : chunk_rows;
    kgemm<<<dim3(MM / 128, rows / 128), 256, 0, stream>>>(normed, base, expchunk);
    kloss<<<rows, 256, 0, stream>>>(expchunk, base, slab, perm, pos,
                                    part_logd, part_sims);
  }
  kreduce<<<1, 256, 0, stream>>>(part_logd, part_sims, out);
}

// Round 3
// 1022.135 us; speedup vs baseline: 1.4442x; 1.4442x over previous
//
#include <hip/hip_runtime.h>
#include <hip/hip_bf16.h>
#include <math.h>

#define MM 4096
#define KK 768

typedef short bf16x8 __attribute__((ext_vector_type(8)));
typedef float f32x4 __attribute__((ext_vector_type(4)));

__device__ __forceinline__ void gload16(const void* g, void* l) {
#if __has_builtin(__builtin_amdgcn_global_load_lds)
  __builtin_amdgcn_global_load_lds((__attribute__((address_space(1))) void*)g,
                                   (__attribute__((address_space(3))) void*)l,
                                   16, 0, 0);
#else
  *(bf16x8*)l = *(const bf16x8*)g;
#endif
}

// ---------------- normalize rows -> bf16 ----------------
__global__ __launch_bounds__(256) void knorm(const float* __restrict__ emb,
                                             __hip_bfloat16* __restrict__ nb) {
  int row = blockIdx.x;
  int tid = threadIdx.x;
  const float* e = emb + (size_t)row * KK;
  float v0 = e[tid], v1 = e[tid + 256], v2 = e[tid + 512];
  float ss = v0 * v0 + v1 * v1 + v2 * v2;
  for (int s = 32; s; s >>= 1) ss += __shfl_down(ss, s, 64);
  __shared__ float red[4];
  if ((tid & 63) == 0) red[tid >> 6] = ss;
  __syncthreads();
  float tot = red[0] + red[1] + red[2] + red[3];
  float inv = 1.f / fmaxf(sqrtf(tot), 1e-12f);
  __hip_bfloat16* o = nb + (size_t)row * KK;
  o[tid] = __float2bfloat16(v0 * inv);
  o[tid + 256] = __float2bfloat16(v1 * inv);
  o[tid + 512] = __float2bfloat16(v2 * inv);
}

// ---------------- rank-sort labels per dim ----------------
__global__ __launch_bounds__(256) void ksort(const float* __restrict__ labels,
                                             float* __restrict__ slab,
                                             int* __restrict__ perm,
                                             int* __restrict__ pos) {
  __shared__ float lab[MM];
  int d = blockIdx.x >> 4;
  int slice = blockIdx.x & 15;
  for (int i = threadIdx.x; i < MM; i += 256) lab[i] = labels[(size_t)i * 2 + d];
  __syncthreads();
  int i = slice * 256 + threadIdx.x;
  float v = lab[i];
  int r = 0;
  for (int k = 0; k < MM; ++k) {
    float w = lab[k];
    r += (w < v) || (w == v && k < i);
  }
  slab[d * MM + r] = v;
  perm[d * MM + r] = i;
  pos[d * MM + i] = r;
}

// ---------------- bf16 MFMA GEMM: exp_sims = exp(sims), srow partials ----------------
// 128x128 tile, BK=32, 256 threads = 4 waves (2x2 of 64x64).
__global__ __launch_bounds__(256) void kgemm(const __hip_bfloat16* __restrict__ A,
                                             int rowBase,
                                             float* __restrict__ out,
                                             float* __restrict__ srow) {
  __shared__ __align__(16) short As[128 * 32];
  __shared__ __align__(16) short Bs[128 * 32];
  const int tid = threadIdx.x;
  const int w = tid >> 6, l = tid & 63;
  const int wr = w >> 1, wc = w & 1;
  const int bx = blockIdx.x;
  const int row0 = rowBase + blockIdx.y * 128;
  const int col0 = bx * 128;
  const short* Ag = (const short*)A;

  f32x4 acc[4][4];
#pragma unroll
  for (int mi = 0; mi < 4; ++mi)
#pragma unroll
    for (int ni = 0; ni < 4; ++ni) acc[mi][ni] = (f32x4){0.f, 0.f, 0.f, 0.f};

  const int r0 = tid >> 2, s0 = tid & 3;                 // slot tid
  const int r1 = (tid + 256) >> 2, s1 = tid & 3;         // slot tid+256
  const int lrow = l & 15, kb = (l >> 4) * 8;

  for (int k0 = 0; k0 < KK; k0 += 32) {
    __syncthreads();
    gload16(Ag + (size_t)(row0 + r0) * KK + k0 + s0 * 8, &As[tid * 8]);
    gload16(Ag + (size_t)(row0 + r1) * KK + k0 + s1 * 8, &As[(tid + 256) * 8]);
    gload16(Ag + (size_t)(col0 + r0) * KK + k0 + s0 * 8, &Bs[tid * 8]);
    gload16(Ag + (size_t)(col0 + r1) * KK + k0 + s1 * 8, &Bs[(tid + 256) * 8]);
    __syncthreads();
    bf16x8 av[4], bv[4];
#pragma unroll
    for (int mi = 0; mi < 4; ++mi)
      av[mi] = *(const bf16x8*)&As[(wr * 64 + mi * 16 + lrow) * 32 + kb];
#pragma unroll
    for (int ni = 0; ni < 4; ++ni)
      bv[ni] = *(const bf16x8*)&Bs[(wc * 64 + ni * 16 + lrow) * 32 + kb];
#pragma unroll
    for (int mi = 0; mi < 4; ++mi)
#pragma unroll
      for (int ni = 0; ni < 4; ++ni)
        acc[mi][ni] = __builtin_amdgcn_mfma_f32_16x16x32_bf16(av[mi], bv[ni],
                                                              acc[mi][ni], 0, 0, 0);
  }

  // epilogue: C/D layout col=lane&15, row=(lane>>4)*4+reg
  const int quad = l >> 4;
#pragma unroll
  for (int mi = 0; mi < 4; ++mi) {
#pragma unroll
    for (int r = 0; r < 4; ++r) {
      const int grow = row0 + wr * 64 + mi * 16 + quad * 4 + r;
      float rsum = 0.f;
#pragma unroll
      for (int ni = 0; ni < 4; ++ni) {
        const int gcol = col0 + wc * 64 + ni * 16 + (l & 15);
        float a = acc[mi][ni][r];
        float s = a / 0.1f;
        out[(size_t)(grow - rowBase) * MM + gcol] = __expf(s);
        rsum += (gcol == grow) ? 0.f : a;
      }
#pragma unroll
      for (int mask = 1; mask < 16; mask <<= 1) rsum += __shfl_xor(rsum, mask, 64);
      if ((l & 15) == 0) srow[(size_t)grow * 64 + bx * 2 + wc] = rsum / 0.1f;
    }
  }
}

// ---------------- per-row loss: sorted-order sweep, two-pointer, register chunks ----
__global__ __launch_bounds__(256) void kloss(const float* __restrict__ expchunk,
                                             int rowBase,
                                             const float* __restrict__ slab_g,
                                             const int* __restrict__ perm_g,
                                             const int* __restrict__ pos_g,
                                             float* __restrict__ part_logd) {
  const int i = rowBase + blockIdx.x;
  const float* row = expchunk + (size_t)blockIdx.x * MM;
  __shared__ float P[MM + 1];   // exclusive prefix sums in sorted order; P[MM]=total
  __shared__ float slab[MM];
  __shared__ float sc[256];
  __shared__ float red[4];
  const int tid = threadIdx.x;
  const int m0 = tid * 16;

  for (int d = 0; d < 2; ++d) {
    __syncthreads();  // protect slab/P/red from previous-phase readers
    for (int m = tid; m < MM; m += 256) slab[m] = slab_g[d * MM + m];

    const int pi = pos_g[d * MM + i];

    // gather exp_sims into sorted order; per-thread contiguous chunk of 16 (registers)
    float g[16];
    {
      const int4* pm4 = (const int4*)(perm_g + d * MM + m0);
      int idx[16];
#pragma unroll
      for (int q = 0; q < 4; ++q) {
        int4 p4 = pm4[q];
        idx[4 * q + 0] = p4.x; idx[4 * q + 1] = p4.y;
        idx[4 * q + 2] = p4.z; idx[4 * q + 3] = p4.w;
      }
#pragma unroll
      for (int u = 0; u < 16; ++u) g[u] = row[idx[u]];
    }
    float ls = 0.f;
#pragma unroll
    for (int u = 0; u < 16; ++u) ls += g[u];
    sc[tid] = ls;
    __syncthreads();
    for (int s = 1; s < 256; s <<= 1) {
      float va = (tid >= s) ? sc[tid - s] : 0.f;
      __syncthreads();
      sc[tid] += va;
      __syncthreads();
    }
    const float total = sc[255];
    float run = (tid > 0) ? sc[tid - 1] : 0.f;
#pragma unroll
    for (int u = 0; u < 16; ++u) {
      P[m0 + u] = run;
      run += g[u];
    }
    if (tid == 0) P[MM] = total;
    __syncthreads();

    const float c = slab[pi];

    float sm[16];
#pragma unroll
    for (int q = 0; q < 4; ++q)
      *(float4*)(sm + 4 * q) = *(const float4*)&slab[m0 + 4 * q];

    // init far pointers: one binary search per side present in chunk
    int loL = pi, hiR = pi;
    {
      int firstR = (m0 + 15 > pi) ? (m0 > pi ? m0 : pi + 1) : -1;
      if (firstR >= 0) {
        float t = slab[firstR] - c;
        int a = 0, b = pi;
        while (a < b) {
          int mid = (a + b) >> 1;
          if (c - slab[mid] < t) b = mid; else a = mid + 1;
        }
        loL = a;
      }
      int firstL = (m0 < pi) ? m0 : -1;
      if (firstL >= 0) {
        float t = c - slab[firstL];
        int a = pi, b = MM;
        while (a < b) {
          int mid = (a + b) >> 1;
          if (slab[mid] - c >= t) b = mid; else a = mid + 1;
        }
        hiR = a;
      }
    }

    float acc = 0.f;
#pragma unroll
    for (int u = 0; u < 16; ++u) {
      const int m = m0 + u;
      if (m == pi) continue;
      const float t = fabsf(sm[u] - c);
      float denom;
      if (t == 0.f) {
        denom = total;
      } else if (m > pi) {
        int hi = m;
        while (hi > pi + 1 && slab[hi - 1] - c >= t) --hi;      // ties only
        while (loL > 0 && c - slab[loL - 1] < t) --loL;
        while (loL < pi && c - slab[loL] >= t) ++loL;
        denom = P[loL] + (total - P[hi]);
      } else {
        int lo = m + 1;
        while (lo < pi && c - slab[lo] >= t) ++lo;              // ties only
        while (hiR > pi && slab[hiR - 1] - c >= t) --hiR;
        while (hiR < MM && slab[hiR] - c < t) ++hiR;
        denom = P[lo] + (total - P[hiR]);
      }
      acc += __logf(fmaxf(denom, 1e-7f));
    }
    for (int s = 32; s; s >>= 1) acc += __shfl_down(acc, s, 64);
    __syncthreads();
    if ((tid & 63) == 0) red[tid >> 6] = acc;
    __syncthreads();
    if (tid == 0) part_logd[d * MM + i] = red[0] + red[1] + red[2] + red[3];
  }
}

// ---------------- final reduce (double) ----------------
__global__ __launch_bounds__(256) void kreduce(const float* __restrict__ part_logd,
                                               const float* __restrict__ srow,
                                               float* __restrict__ out) {
  int tid = threadIdx.x;
  double s0 = 0.0, s1 = 0.0, ss = 0.0;
  for (int i = tid; i < MM; i += 256) {
    s0 += (double)part_logd[i];
    s1 += (double)part_logd[MM + i];
    float rs = 0.f;
    for (int q = 0; q < 64; ++q) rs += srow[(size_t)i * 64 + q];
    ss += (double)rs;
  }
  for (int s = 32; s; s >>= 1) {
    s0 += __shfl_down(s0, s, 64);
    s1 += __shfl_down(s1, s, 64);
    ss += __shfl_down(ss, s, 64);
  }
  __shared__ double red[3][4];
  if ((tid & 63) == 0) {
    red[0][tid >> 6] = s0;
    red[1][tid >> 6] = s1;
    red[2][tid >> 6] = ss;
  }
  __syncthreads();
  if (tid == 0) {
    double t0 = red[0][0] + red[0][1] + red[0][2] + red[0][3];
    double t1 = red[1][0] + red[1][1] + red[1][2] + red[1][3];
    double ts = red[2][0] + red[2][1] + red[2][2] + red[2][3];
    double n = (double)MM * (double)(MM - 1);
    out[0] = (float)((t0 - ts) / n);
    out[1] = (float)((t1 - ts) / n);
  }
}

extern "C" void kernel_launch(void* const* d_in, const int* in_sizes, int n_in,
                              void* d_out, int out_size, void* d_ws, size_t ws_size,
                              hipStream_t stream) {
  const float* emb = (const float*)d_in[0];
  const float* labels = (const float*)d_in[1];
  float* out = (float*)d_out;
  char* ws = (char*)d_ws;

  size_t off = 0;
  auto alloc = [&](size_t bytes) {
    void* p = ws + off;
    off = (off + bytes + 255) & ~(size_t)255;
    return p;
  };
  __hip_bfloat16* nb = (__hip_bfloat16*)alloc((size_t)MM * KK * 2);
  float* slab = (float*)alloc((size_t)2 * MM * 4);
  int* perm = (int*)alloc((size_t)2 * MM * 4);
  int* pos = (int*)alloc((size_t)2 * MM * 4);
  float* part_logd = (float*)alloc((size_t)2 * MM * 4);
  float* srow = (float*)alloc((size_t)MM * 64 * 4);
  size_t fixed = off;

  size_t avail = (ws_size > fixed) ? (ws_size - fixed) : 0;
  long long cr = (long long)(avail / ((size_t)MM * 4));
  cr = (cr / 128) * 128;
  if (cr > MM) cr = MM;
  if (cr < 128) cr = 128;
  int chunk_rows = (int)cr;
  float* expchunk = (float*)(ws + fixed);

  knorm<<<MM, 256, 0, stream>>>(emb, nb);
  ksort<<<32, 256, 0, stream>>>(labels, slab, perm, pos);

  for (int base = 0; base < MM; base += chunk_rows) {
    int rows = MM - base < chunk_rows ? MM - base : chunk_rows;
    kgemm<<<dim3(MM / 128, rows / 128), 256, 0, stream>>>(nb, base, expchunk, srow);
    kloss<<<rows, 256, 0, stream>>>(expchunk, base, slab, perm, pos, part_logd);
  }
  kreduce<<<1, 256, 0, stream>>>(part_logd, srow, out);
}

// Round 4
// 693.906 us; speedup vs baseline: 2.1274x; 1.4730x over previous
//
#include <hip/hip_runtime.h>
#include <hip/hip_bf16.h>
#include <math.h>

#define MM 4096
#define KK 768
#define PADI(m) ((m) + ((m) >> 4))

typedef short bf16x8 __attribute__((ext_vector_type(8)));
typedef float f32x4 __attribute__((ext_vector_type(4)));

__device__ __forceinline__ void gload16(const void* g, void* l) {
#if __has_builtin(__builtin_amdgcn_global_load_lds)
  __builtin_amdgcn_global_load_lds((__attribute__((address_space(1))) void*)g,
                                   (__attribute__((address_space(3))) void*)l,
                                   16, 0, 0);
#else
  *(bf16x8*)l = *(const bf16x8*)g;
#endif
}

// ---------------- normalize rows -> bf16 ----------------
__global__ __launch_bounds__(256) void knorm(const float* __restrict__ emb,
                                             __hip_bfloat16* __restrict__ nb) {
  int row = blockIdx.x;
  int tid = threadIdx.x;
  const float* e = emb + (size_t)row * KK;
  float v0 = e[tid], v1 = e[tid + 256], v2 = e[tid + 512];
  float ss = v0 * v0 + v1 * v1 + v2 * v2;
  for (int s = 32; s; s >>= 1) ss += __shfl_down(ss, s, 64);
  __shared__ float red[4];
  if ((tid & 63) == 0) red[tid >> 6] = ss;
  __syncthreads();
  float tot = red[0] + red[1] + red[2] + red[3];
  float inv = 1.f / fmaxf(sqrtf(tot), 1e-12f);
  __hip_bfloat16* o = nb + (size_t)row * KK;
  o[tid] = __float2bfloat16(v0 * inv);
  o[tid + 256] = __float2bfloat16(v1 * inv);
  o[tid + 512] = __float2bfloat16(v2 * inv);
}

// ---------------- rank-sort labels per dim ----------------
__global__ __launch_bounds__(256) void ksort(const float* __restrict__ labels,
                                             float* __restrict__ slab,
                                             int* __restrict__ perm,
                                             int* __restrict__ pos) {
  __shared__ float lab[MM];
  int d = blockIdx.x >> 4;
  int slice = blockIdx.x & 15;
  for (int i = threadIdx.x; i < MM; i += 256) lab[i] = labels[(size_t)i * 2 + d];
  __syncthreads();
  int i = slice * 256 + threadIdx.x;
  float v = lab[i];
  int r = 0;
  for (int k = 0; k < MM; ++k) {
    float w = lab[k];
    r += (w < v) || (w == v && k < i);
  }
  slab[d * MM + r] = v;
  perm[d * MM + r] = i;
  pos[d * MM + i] = r;
}

// ---------------- bf16 MFMA GEMM: exp_sims = exp(sims), srow partials ----------------
__global__ __launch_bounds__(256) void kgemm(const __hip_bfloat16* __restrict__ A,
                                             int rowBase,
                                             float* __restrict__ out,
                                             float* __restrict__ srow) {
  __shared__ __align__(16) short As[128 * 32];
  __shared__ __align__(16) short Bs[128 * 32];
  const int tid = threadIdx.x;
  const int w = tid >> 6, l = tid & 63;
  const int wr = w >> 1, wc = w & 1;
  const int bx = blockIdx.x;
  const int row0 = rowBase + blockIdx.y * 128;
  const int col0 = bx * 128;
  const short* Ag = (const short*)A;

  f32x4 acc[4][4];
#pragma unroll
  for (int mi = 0; mi < 4; ++mi)
#pragma unroll
    for (int ni = 0; ni < 4; ++ni) acc[mi][ni] = (f32x4){0.f, 0.f, 0.f, 0.f};

  const int r0 = tid >> 2, s0 = tid & 3;
  const int r1 = (tid + 256) >> 2, s1 = tid & 3;
  const int lrow = l & 15, kb = (l >> 4) * 8;

  for (int k0 = 0; k0 < KK; k0 += 32) {
    __syncthreads();
    gload16(Ag + (size_t)(row0 + r0) * KK + k0 + s0 * 8, &As[tid * 8]);
    gload16(Ag + (size_t)(row0 + r1) * KK + k0 + s1 * 8, &As[(tid + 256) * 8]);
    gload16(Ag + (size_t)(col0 + r0) * KK + k0 + s0 * 8, &Bs[tid * 8]);
    gload16(Ag + (size_t)(col0 + r1) * KK + k0 + s1 * 8, &Bs[(tid + 256) * 8]);
    __syncthreads();
    bf16x8 av[4], bv[4];
#pragma unroll
    for (int mi = 0; mi < 4; ++mi)
      av[mi] = *(const bf16x8*)&As[(wr * 64 + mi * 16 + lrow) * 32 + kb];
#pragma unroll
    for (int ni = 0; ni < 4; ++ni)
      bv[ni] = *(const bf16x8*)&Bs[(wc * 64 + ni * 16 + lrow) * 32 + kb];
#pragma unroll
    for (int mi = 0; mi < 4; ++mi)
#pragma unroll
      for (int ni = 0; ni < 4; ++ni)
        acc[mi][ni] = __builtin_amdgcn_mfma_f32_16x16x32_bf16(av[mi], bv[ni],
                                                              acc[mi][ni], 0, 0, 0);
  }

  const int quad = l >> 4;
#pragma unroll
  for (int mi = 0; mi < 4; ++mi) {
#pragma unroll
    for (int r = 0; r < 4; ++r) {
      const int grow = row0 + wr * 64 + mi * 16 + quad * 4 + r;
      float rsum = 0.f;
#pragma unroll
      for (int ni = 0; ni < 4; ++ni) {
        const int gcol = col0 + wc * 64 + ni * 16 + (l & 15);
        float a = acc[mi][ni][r];
        float s = a / 0.1f;
        out[(size_t)(grow - rowBase) * MM + gcol] = __expf(s);
        rsum += (gcol == grow) ? 0.f : a;
      }
#pragma unroll
      for (int mask = 1; mask < 16; mask <<= 1) rsum += __shfl_xor(rsum, mask, 64);
      if ((l & 15) == 0) srow[(size_t)grow * 64 + bx * 2 + wc] = rsum / 0.1f;
    }
  }
}

// ---------------- per-row loss: independent interleaved searches ----------------
__global__ __launch_bounds__(256) void kloss(const float* __restrict__ expchunk,
                                             int rowBase,
                                             const float* __restrict__ slab_g,
                                             const int* __restrict__ perm_g,
                                             const int* __restrict__ pos_g,
                                             float* __restrict__ part_logd) {
  const int i = rowBase + blockIdx.x;
  const float* row = expchunk + (size_t)blockIdx.x * MM;
  __shared__ float P[PADI(MM) + 1];   // padded exclusive prefix sums; P[PADI(MM)] = total
  __shared__ float slab[MM];
  __shared__ float sc[256];
  __shared__ float red[4];
  const int tid = threadIdx.x;
  const int m0 = tid * 16;

  for (int d = 0; d < 2; ++d) {
    __syncthreads();
    for (int m = tid; m < MM; m += 256) slab[m] = slab_g[d * MM + m];

    const int pi = pos_g[d * MM + i];

    // gather exp_sims into sorted order (registers, constant-indexed)
    float g[16];
    {
      const int4* pm4 = (const int4*)(perm_g + d * MM + m0);
      int idx[16];
#pragma unroll
      for (int q = 0; q < 4; ++q) {
        int4 p4 = pm4[q];
        idx[4 * q + 0] = p4.x; idx[4 * q + 1] = p4.y;
        idx[4 * q + 2] = p4.z; idx[4 * q + 3] = p4.w;
      }
#pragma unroll
      for (int u = 0; u < 16; ++u) g[u] = row[idx[u]];
    }
    float ls = 0.f;
#pragma unroll
    for (int u = 0; u < 16; ++u) ls += g[u];
    sc[tid] = ls;
    __syncthreads();
    for (int s = 1; s < 256; s <<= 1) {
      float va = (tid >= s) ? sc[tid - s] : 0.f;
      __syncthreads();
      sc[tid] += va;
      __syncthreads();
    }
    const float total = sc[255];
    float run = (tid > 0) ? sc[tid - 1] : 0.f;
#pragma unroll
    for (int u = 0; u < 16; ++u) {
      P[PADI(m0 + u)] = run;
      run += g[u];
    }
    if (tid == 0) P[PADI(MM)] = total;
    __syncthreads();

    const float c = slab[pi];

    // register copy of this chunk's sorted labels + distances
    float sm[16];
#pragma unroll
    for (int q = 0; q < 4; ++q)
      *(float4*)(sm + 4 * q) = *(const float4*)&slab[m0 + 4 * q];
    float tv[16];
#pragma unroll
    for (int u = 0; u < 16; ++u) tv[u] = fabsf(sm[u] - c);

    // near boundaries: element itself +- tie-walk (first check from registers)
    int nb[16];
#pragma unroll
    for (int u = 0; u < 16; ++u) {
      const int m = m0 + u;
      int b = 0;
      if (m > pi) {
        int hi = m;
        if (m - 1 > pi) {
          float pv = (u > 0) ? sm[u - 1] : slab[m - 1];
          if (pv - c >= tv[u]) {           // tie: walk down (rare)
            hi = m - 1;
            while (hi - 1 > pi && slab[hi - 1] - c >= tv[u]) --hi;
          }
        }
        b = hi;
      } else if (m < pi) {
        int lo = m + 1;
        if (m + 1 < pi) {
          float nv = (u < 15) ? sm[u + 1] : slab[m + 1];
          if (c - nv >= tv[u]) {           // tie: walk up (rare)
            lo = m + 2;
            while (lo < pi && c - slab[lo] >= tv[u]) ++lo;
          }
        }
        b = lo;
      }
      nb[u] = b;
    }

    // far boundaries: 2 batches of 8 independent binary searches, lockstep
    int far[16];
#pragma unroll
    for (int b8 = 0; b8 < 2; ++b8) {
      int A[8], B[8];
      float T[8];
#pragma unroll
      for (int q = 0; q < 8; ++q) {
        const int u = b8 * 8 + q;
        const int m = m0 + u;
        T[q] = tv[u];
        if (m == pi || tv[u] == 0.f) { A[q] = 0; B[q] = 0; }
        else if (m > pi) { A[q] = 0; B[q] = pi; }      // find first c-slab < t in [0,pi]
        else { A[q] = pi; B[q] = MM; }                 // find first slab-c >= t in [pi,MM]
      }
      const int flag = (b8 * 8 + 7 + m0 > pi) ? 1 : 0; (void)flag;
#pragma unroll
      for (int s = 0; s < 12; ++s) {
#pragma unroll
        for (int q = 0; q < 8; ++q) {
          if (A[q] < B[q]) {
            const int mid = (A[q] + B[q]) >> 1;
            const float v = slab[mid];
            const bool isR = (m0 + b8 * 8 + q) > pi;
            const bool pr = isR ? (c - v < T[q]) : (v - c >= T[q]);
            if (pr) B[q] = mid; else A[q] = mid + 1;
          }
        }
      }
#pragma unroll
      for (int q = 0; q < 8; ++q) far[b8 * 8 + q] = A[q];
    }

    float acc = 0.f;
#pragma unroll
    for (int u = 0; u < 16; ++u) {
      const int m = m0 + u;
      if (m == pi) continue;
      float denom;
      if (tv[u] == 0.f) {
        denom = total;
      } else if (m > pi) {
        denom = P[PADI(far[u])] + (total - P[PADI(nb[u])]);
      } else {
        denom = P[PADI(nb[u])] + (total - P[PADI(far[u])]);
      }
      acc += __logf(fmaxf(denom, 1e-7f));
    }
    for (int s = 32; s; s >>= 1) acc += __shfl_down(acc, s, 64);
    __syncthreads();
    if ((tid & 63) == 0) red[tid >> 6] = acc;
    __syncthreads();
    if (tid == 0) part_logd[d * MM + i] = red[0] + red[1] + red[2] + red[3];
  }
}

// ---------------- final reduce (double) ----------------
__global__ __launch_bounds__(256) void kreduce(const float* __restrict__ part_logd,
                                               const float* __restrict__ srow,
                                               float* __restrict__ out) {
  int tid = threadIdx.x;
  double s0 = 0.0, s1 = 0.0, ss = 0.0;
  for (int i = tid; i < MM; i += 256) {
    s0 += (double)part_logd[i];
    s1 += (double)part_logd[MM + i];
    float rs = 0.f;
    for (int q = 0; q < 64; ++q) rs += srow[(size_t)i * 64 + q];
    ss += (double)rs;
  }
  for (int s = 32; s; s >>= 1) {
    s0 += __shfl_down(s0, s, 64);
    s1 += __shfl_down(s1, s, 64);
    ss += __shfl_down(ss, s, 64);
  }
  __shared__ double red[3][4];
  if ((tid & 63) == 0) {
    red[0][tid >> 6] = s0;
    red[1][tid >> 6] = s1;
    red[2][tid >> 6] = ss;
  }
  __syncthreads();
  if (tid == 0) {
    double t0 = red[0][0] + red[0][1] + red[0][2] + red[0][3];
    double t1 = red[1][0] + red[1][1] + red[1][2] + red[1][3];
    double ts = red[2][0] + red[2][1] + red[2][2] + red[2][3];
    double n = (double)MM * (double)(MM - 1);
    out[0] = (float)((t0 - ts) / n);
    out[1] = (float)((t1 - ts) / n);
  }
}

extern "C" void kernel_launch(void* const* d_in, const int* in_sizes, int n_in,
                              void* d_out, int out_size, void* d_ws, size_t ws_size,
                              hipStream_t stream) {
  const float* emb = (const float*)d_in[0];
  const float* labels = (const float*)d_in[1];
  float* out = (float*)d_out;
  char* ws = (char*)d_ws;

  size_t off = 0;
  auto alloc = [&](size_t bytes) {
    void* p = ws + off;
    off = (off + bytes + 255) & ~(size_t)255;
    return p;
  };
  __hip_bfloat16* nb = (__hip_bfloat16*)alloc((size_t)MM * KK * 2);
  float* slab = (float*)alloc((size_t)2 * MM * 4);
  int* perm = (int*)alloc((size_t)2 * MM * 4);
  int* pos = (int*)alloc((size_t)2 * MM * 4);
  float* part_logd = (float*)alloc((size_t)2 * MM * 4);
  float* srow = (float*)alloc((size_t)MM * 64 * 4);
  size_t fixed = off;

  size_t avail = (ws_size > fixed) ? (ws_size - fixed) : 0;
  long long cr = (long long)(avail / ((size_t)MM * 4));
  cr = (cr / 128) * 128;
  if (cr > MM) cr = MM;
  if (cr < 128) cr = 128;
  int chunk_rows = (int)cr;
  float* expchunk = (float*)(ws + fixed);

  knorm<<<MM, 256, 0, stream>>>(emb, nb);
  ksort<<<32, 256, 0, stream>>>(labels, slab, perm, pos);

  for (int base = 0; base < MM; base += chunk_rows) {
    int rows = MM - base < chunk_rows ? MM - base : chunk_rows;
    kgemm<<<dim3(MM / 128, rows / 128), 256, 0, stream>>>(nb, base, expchunk, srow);
    kloss<<<rows, 256, 0, stream>>>(expchunk, base, slab, perm, pos, part_logd);
  }
  kreduce<<<1, 256, 0, stream>>>(part_logd, srow, out);
}

// Round 5
// 251.746 us; speedup vs baseline: 5.8638x; 2.7564x over previous
//
#include <hip/hip_runtime.h>
#include <hip/hip_bf16.h>
#include <math.h>

#define MM 4096
#define KK 768
#define PADI(m) ((m) + ((m) >> 4))

typedef short bf16x8 __attribute__((ext_vector_type(8)));
typedef float f32x4 __attribute__((ext_vector_type(4)));

__device__ __forceinline__ void gload16(const void* g, void* l) {
#if __has_builtin(__builtin_amdgcn_global_load_lds)
  __builtin_amdgcn_global_load_lds((__attribute__((address_space(1))) void*)g,
                                   (__attribute__((address_space(3))) void*)l,
                                   16, 0, 0);
#else
  *(bf16x8*)l = *(const bf16x8*)g;
#endif
}

// ---------------- normalize rows -> bf16 ----------------
__global__ __launch_bounds__(256) void knorm(const float* __restrict__ emb,
                                             __hip_bfloat16* __restrict__ nb) {
  int row = blockIdx.x;
  int tid = threadIdx.x;
  const float* e = emb + (size_t)row * KK;
  float v0 = e[tid], v1 = e[tid + 256], v2 = e[tid + 512];
  float ss = v0 * v0 + v1 * v1 + v2 * v2;
  for (int s = 32; s; s >>= 1) ss += __shfl_down(ss, s, 64);
  __shared__ float red[4];
  if ((tid & 63) == 0) red[tid >> 6] = ss;
  __syncthreads();
  float tot = red[0] + red[1] + red[2] + red[3];
  float inv = 1.f / fmaxf(sqrtf(tot), 1e-12f);
  __hip_bfloat16* o = nb + (size_t)row * KK;
  o[tid] = __float2bfloat16(v0 * inv);
  o[tid + 256] = __float2bfloat16(v1 * inv);
  o[tid + 512] = __float2bfloat16(v2 * inv);
}

// ---------------- rank-sort labels per dim ----------------
__global__ __launch_bounds__(256) void ksort(const float* __restrict__ labels,
                                             float* __restrict__ slab,
                                             int* __restrict__ perm,
                                             int* __restrict__ pos) {
  __shared__ float lab[MM];
  int d = blockIdx.x >> 4;
  int slice = blockIdx.x & 15;
  for (int i = threadIdx.x; i < MM; i += 256) lab[i] = labels[(size_t)i * 2 + d];
  __syncthreads();
  int i = slice * 256 + threadIdx.x;
  float v = lab[i];
  int r = 0;
  for (int k = 0; k < MM; ++k) {
    float w = lab[k];
    r += (w < v) || (w == v && k < i);
  }
  slab[d * MM + r] = v;
  perm[d * MM + r] = i;
  pos[d * MM + i] = r;
}

// ---------------- bf16 MFMA GEMM: exp_sims = exp(sims), srow partials ----------------
__global__ __launch_bounds__(256) void kgemm(const __hip_bfloat16* __restrict__ A,
                                             int rowBase,
                                             float* __restrict__ out,
                                             float* __restrict__ srow) {
  __shared__ __align__(16) short As[128 * 32];
  __shared__ __align__(16) short Bs[128 * 32];
  const int tid = threadIdx.x;
  const int w = tid >> 6, l = tid & 63;
  const int wr = w >> 1, wc = w & 1;
  const int bx = blockIdx.x;
  const int row0 = rowBase + blockIdx.y * 128;
  const int col0 = bx * 128;
  const short* Ag = (const short*)A;

  f32x4 acc[4][4];
#pragma unroll
  for (int mi = 0; mi < 4; ++mi)
#pragma unroll
    for (int ni = 0; ni < 4; ++ni) acc[mi][ni] = (f32x4){0.f, 0.f, 0.f, 0.f};

  const int r0 = tid >> 2, s0 = tid & 3;
  const int r1 = (tid + 256) >> 2, s1 = tid & 3;
  const int lrow = l & 15, kb = (l >> 4) * 8;

  for (int k0 = 0; k0 < KK; k0 += 32) {
    __syncthreads();
    gload16(Ag + (size_t)(row0 + r0) * KK + k0 + s0 * 8, &As[tid * 8]);
    gload16(Ag + (size_t)(row0 + r1) * KK + k0 + s1 * 8, &As[(tid + 256) * 8]);
    gload16(Ag + (size_t)(col0 + r0) * KK + k0 + s0 * 8, &Bs[tid * 8]);
    gload16(Ag + (size_t)(col0 + r1) * KK + k0 + s1 * 8, &Bs[(tid + 256) * 8]);
    __syncthreads();
    bf16x8 av[4], bv[4];
#pragma unroll
    for (int mi = 0; mi < 4; ++mi)
      av[mi] = *(const bf16x8*)&As[(wr * 64 + mi * 16 + lrow) * 32 + kb];
#pragma unroll
    for (int ni = 0; ni < 4; ++ni)
      bv[ni] = *(const bf16x8*)&Bs[(wc * 64 + ni * 16 + lrow) * 32 + kb];
#pragma unroll
    for (int mi = 0; mi < 4; ++mi)
#pragma unroll
      for (int ni = 0; ni < 4; ++ni)
        acc[mi][ni] = __builtin_amdgcn_mfma_f32_16x16x32_bf16(av[mi], bv[ni],
                                                              acc[mi][ni], 0, 0, 0);
  }

  const int quad = l >> 4;
#pragma unroll
  for (int mi = 0; mi < 4; ++mi) {
#pragma unroll
    for (int r = 0; r < 4; ++r) {
      const int grow = row0 + wr * 64 + mi * 16 + quad * 4 + r;
      float rsum = 0.f;
#pragma unroll
      for (int ni = 0; ni < 4; ++ni) {
        const int gcol = col0 + wc * 64 + ni * 16 + (l & 15);
        float a = acc[mi][ni][r];
        float s = a / 0.1f;
        out[(size_t)(grow - rowBase) * MM + gcol] = __expf(s);
        rsum += (gcol == grow) ? 0.f : a;
      }
#pragma unroll
      for (int mask = 1; mask < 16; mask <<= 1) rsum += __shfl_xor(rsum, mask, 64);
      if ((l & 15) == 0) srow[(size_t)grow * 64 + bx * 2 + wc] = rsum / 0.1f;
    }
  }
}

// ---------------- per-row loss: merge-path over distance order ----------------
__global__ __launch_bounds__(256) void kloss(const float* __restrict__ expchunk,
                                             int rowBase,
                                             const float* __restrict__ slab_g,
                                             const int* __restrict__ perm_g,
                                             const int* __restrict__ pos_g,
                                             float* __restrict__ part_logd) {
  const int i = rowBase + blockIdx.x;
  const float* row = expchunk + (size_t)blockIdx.x * MM;
  __shared__ float P[PADI(MM) + 1];   // padded exclusive prefix in sorted-label order
  __shared__ float slab[MM];
  __shared__ float wsum[4];
  __shared__ float red[4];
  const int tid = threadIdx.x;
  const int lane = tid & 63, wid = tid >> 6;
  const int m0 = tid * 16;

  for (int d = 0; d < 2; ++d) {
    __syncthreads();   // protect slab/P/red from previous-phase readers
    for (int m = tid; m < MM; m += 256) slab[m] = slab_g[d * MM + m];

    const int pi = pos_g[d * MM + i];

    // gather exp_sims into sorted order (registers)
    float g[16];
    {
      const int4* pm4 = (const int4*)(perm_g + d * MM + m0);
      int idx[16];
#pragma unroll
      for (int q = 0; q < 4; ++q) {
        int4 p4 = pm4[q];
        idx[4 * q + 0] = p4.x; idx[4 * q + 1] = p4.y;
        idx[4 * q + 2] = p4.z; idx[4 * q + 3] = p4.w;
      }
#pragma unroll
      for (int u = 0; u < 16; ++u) g[u] = row[idx[u]];
    }
    float ls = 0.f;
#pragma unroll
    for (int u = 0; u < 16; ++u) ls += g[u];

    // wave-level inclusive scan of per-thread sums (no LDS ping-pong)
    float v = ls;
#pragma unroll
    for (int s = 1; s < 64; s <<= 1) {
      float t = __shfl_up(v, s, 64);
      if (lane >= s) v += t;
    }
    if (lane == 63) wsum[wid] = v;
    __syncthreads();
    float woff = 0.f;
#pragma unroll
    for (int q = 0; q < 4; ++q) woff += (q < wid) ? wsum[q] : 0.f;
    const float total = wsum[0] + wsum[1] + wsum[2] + wsum[3];
    float run = woff + (v - ls);   // exclusive prefix for this thread's chunk
#pragma unroll
    for (int u = 0; u < 16; ++u) {
      P[PADI(m0 + u)] = run;
      run += g[u];
    }
    if (tid == 0) P[PADI(MM)] = total;
    __syncthreads();

    const float c = slab[pi];
    const float gC = row[i];       // center's exp value (dist == 0 inclusion)

    // ---- merge-path diagonal partition: rank k0r in the distance-merge ----
    const int nB = MM - 1 - pi;
    const int k0r = m0;            // merged-rank start for this thread
    int aLo = k0r - nB; if (aLo < 0) aLo = 0;
    int aHi = (k0r < pi) ? k0r : pi;
    while (aLo < aHi) {
      const int mid = (aLo + aHi) >> 1;
      const float Aa = c - slab[pi - 1 - mid];          // left dist (ascending in mid)
      const float Bb = slab[pi + k0r - mid] - c;        // right dist B[k0r-1-mid]
      if (Aa > Bb) aHi = mid; else aLo = mid + 1;
    }
    int Lp = pi - 1 - aLo;           // next left index to consume
    int Rp = pi + 1 + (k0r - aLo);   // next right index to consume

    float tL = (Lp >= 0) ? (c - slab[Lp]) : INFINITY;
    float tR = (Rp < MM) ? (slab[Rp] - c) : INFINITY;
    float lastLD = -1.f, lastRD = -1.f;
    int lastLo = 0, lastHi = 0;
    float acc = 0.f;
    const int cnt = (MM - 1 - k0r < 16) ? (MM - 1 - k0r) : 16;
    for (int step = 0; step < cnt; ++step) {
      const bool left = (tL <= tR);
      const float t = left ? tL : tR;
      int lo, hi;
      if (left) {                       // consume left element Lp, dist t
        lo = (t == lastLD) ? lastLo : (Lp + 1);   // include self + unconsumed + tie-run
        hi = Rp;                                  // right ties are still unconsumed
        lastLD = t; lastLo = lo;
      } else {                          // consume right element Rp, dist t
        hi = (t == lastRD) ? lastHi : Rp;         // right tie-run start
        lo = (t == lastLD) ? lastLo : (Lp + 1);   // include consumed left ties
        lastRD = t; lastHi = hi;
      }
      float denom = P[PADI(lo)] + (total - P[PADI(hi)]) + ((t == 0.f) ? gC : 0.f);
      acc += __logf(fmaxf(denom, 1e-7f));
      if (left) { --Lp; tL = (Lp >= 0) ? (c - slab[Lp]) : INFINITY; }
      else      { ++Rp; tR = (Rp < MM) ? (slab[Rp] - c) : INFINITY; }
    }

    for (int s = 32; s; s >>= 1) acc += __shfl_down(acc, s, 64);
    __syncthreads();
    if ((tid & 63) == 0) red[tid >> 6] = acc;
    __syncthreads();
    if (tid == 0) part_logd[d * MM + i] = red[0] + red[1] + red[2] + red[3];
  }
}

// ---------------- two-stage final reduce (double) ----------------
__global__ __launch_bounds__(256) void kred1(const float* __restrict__ part_logd,
                                             const float* __restrict__ srow,
                                             double* __restrict__ red3) {
  const int tid = threadIdx.x;
  const int base = blockIdx.x * 64;   // 64 rows per block
  double ss = 0.0, s0 = 0.0, s1 = 0.0;
  for (int q = tid; q < 64 * 64; q += 256)
    ss += (double)srow[(size_t)base * 64 + q];
  if (tid < 64) {
    s0 = (double)part_logd[base + tid];
    s1 = (double)part_logd[MM + base + tid];
  }
  for (int s = 32; s; s >>= 1) {
    s0 += __shfl_down(s0, s, 64);
    s1 += __shfl_down(s1, s, 64);
    ss += __shfl_down(ss, s, 64);
  }
  __shared__ double red[3][4];
  if ((tid & 63) == 0) {
    red[0][tid >> 6] = s0; red[1][tid >> 6] = s1; red[2][tid >> 6] = ss;
  }
  __syncthreads();
  if (tid == 0) {
    red3[blockIdx.x * 3 + 0] = red[0][0] + red[0][1] + red[0][2] + red[0][3];
    red3[blockIdx.x * 3 + 1] = red[1][0] + red[1][1] + red[1][2] + red[1][3];
    red3[blockIdx.x * 3 + 2] = red[2][0] + red[2][1] + red[2][2] + red[2][3];
  }
}

__global__ __launch_bounds__(64) void kred2(const double* __restrict__ red3,
                                            float* __restrict__ out) {
  const int t = threadIdx.x;  // 64 threads, 64 partials
  double s0 = red3[t * 3 + 0], s1 = red3[t * 3 + 1], ss = red3[t * 3 + 2];
  for (int s = 32; s; s >>= 1) {
    s0 += __shfl_down(s0, s, 64);
    s1 += __shfl_down(s1, s, 64);
    ss += __shfl_down(ss, s, 64);
  }
  if (t == 0) {
    const double n = (double)MM * (double)(MM - 1);
    out[0] = (float)((s0 - ss) / n);
    out[1] = (float)((s1 - ss) / n);
  }
}

extern "C" void kernel_launch(void* const* d_in, const int* in_sizes, int n_in,
                              void* d_out, int out_size, void* d_ws, size_t ws_size,
                              hipStream_t stream) {
  const float* emb = (const float*)d_in[0];
  const float* labels = (const float*)d_in[1];
  float* out = (float*)d_out;
  char* ws = (char*)d_ws;

  size_t off = 0;
  auto alloc = [&](size_t bytes) {
    void* p = ws + off;
    off = (off + bytes + 255) & ~(size_t)255;
    return p;
  };
  __hip_bfloat16* nb = (__hip_bfloat16*)alloc((size_t)MM * KK * 2);
  float* slab = (float*)alloc((size_t)2 * MM * 4);
  int* perm = (int*)alloc((size_t)2 * MM * 4);
  int* pos = (int*)alloc((size_t)2 * MM * 4);
  float* part_logd = (float*)alloc((size_t)2 * MM * 4);
  float* srow = (float*)alloc((size_t)MM * 64 * 4);
  double* red3 = (double*)alloc((size_t)64 * 3 * 8);
  size_t fixed = off;

  size_t avail = (ws_size > fixed) ? (ws_size - fixed) : 0;
  long long cr = (long long)(avail / ((size_t)MM * 4));
  cr = (cr / 128) * 128;
  if (cr > MM) cr = MM;
  if (cr < 128) cr = 128;
  int chunk_rows = (int)cr;
  float* expchunk = (float*)(ws + fixed);

  knorm<<<MM, 256, 0, stream>>>(emb, nb);
  ksort<<<32, 256, 0, stream>>>(labels, slab, perm, pos);

  for (int base = 0; base < MM; base += chunk_rows) {
    int rows = MM - base < chunk_rows ? MM - base : chunk_rows;
    kgemm<<<dim3(MM / 128, rows / 128), 256, 0, stream>>>(nb, base, expchunk, srow);
    kloss<<<rows, 256, 0, stream>>>(expchunk, base, slab, perm, pos, part_logd);
  }
  kred1<<<64, 256, 0, stream>>>(part_logd, srow, red3);
  kred2<<<1, 64, 0, stream>>>(red3, out);
}

// Round 6
// 163.961 us; speedup vs baseline: 9.0033x; 1.5354x over previous
//
#include <hip/hip_runtime.h>
#include <hip/hip_bf16.h>
#include <math.h>

#define MM 4096
#define KK 768
#define PADI(m) ((m) + ((m) >> 4))

typedef short bf16x8 __attribute__((ext_vector_type(8)));
typedef float f32x4 __attribute__((ext_vector_type(4)));

__device__ __forceinline__ void gload16(const void* g, void* l) {
#if __has_builtin(__builtin_amdgcn_global_load_lds)
  __builtin_amdgcn_global_load_lds((__attribute__((address_space(1))) void*)g,
                                   (__attribute__((address_space(3))) void*)l,
                                   16, 0, 0);
#else
  *(bf16x8*)l = *(const bf16x8*)g;
#endif
}

// ---------------- normalize rows -> bf16 ----------------
__global__ __launch_bounds__(256) void knorm(const float* __restrict__ emb,
                                             __hip_bfloat16* __restrict__ nb) {
  int row = blockIdx.x;
  int tid = threadIdx.x;
  const float* e = emb + (size_t)row * KK;
  float v0 = e[tid], v1 = e[tid + 256], v2 = e[tid + 512];
  float ss = v0 * v0 + v1 * v1 + v2 * v2;
  for (int s = 32; s; s >>= 1) ss += __shfl_down(ss, s, 64);
  __shared__ float red[4];
  if ((tid & 63) == 0) red[tid >> 6] = ss;
  __syncthreads();
  float tot = red[0] + red[1] + red[2] + red[3];
  float inv = 1.f / fmaxf(sqrtf(tot), 1e-12f);
  __hip_bfloat16* o = nb + (size_t)row * KK;
  o[tid] = __float2bfloat16(v0 * inv);
  o[tid + 256] = __float2bfloat16(v1 * inv);
  o[tid + 512] = __float2bfloat16(v2 * inv);
}

// ---------------- rank labels: 256x256 tiles, partial counts via atomics ----------
__global__ __launch_bounds__(256) void krank(const float* __restrict__ labels,
                                             int* __restrict__ rank) {
  __shared__ float lab[256];
  const int slice = blockIdx.x, chunk = blockIdx.y, d = blockIdx.z;
  const int tid = threadIdx.x;
  const int kg0 = chunk * 256;
  lab[tid] = labels[(size_t)(kg0 + tid) * 2 + d];
  const int i = slice * 256 + tid;
  const float v = labels[(size_t)i * 2 + d];
  __syncthreads();
  int r = 0;
#pragma unroll 8
  for (int k = 0; k < 256; ++k) {
    const float w = lab[k];
    r += (w < v) || (w == v && (kg0 + k) < i);
  }
  atomicAdd(&rank[d * MM + i], r);
}

// ---------------- scatter into sorted arrays ----------------
__global__ __launch_bounds__(256) void kscatter(const float* __restrict__ labels,
                                                const int* __restrict__ rank,
                                                float* __restrict__ slab,
                                                int* __restrict__ perm,
                                                int* __restrict__ pos) {
  const int d = blockIdx.x >> 4;
  const int i = (blockIdx.x & 15) * 256 + threadIdx.x;
  const int r = rank[d * MM + i];
  slab[d * MM + r] = labels[(size_t)i * 2 + d];
  perm[d * MM + r] = i;
  pos[d * MM + i] = r;
}

// ---------------- bf16 MFMA GEMM: exp_sims = exp(sims), srow partials ----------------
__global__ __launch_bounds__(256) void kgemm(const __hip_bfloat16* __restrict__ A,
                                             int rowBase,
                                             float* __restrict__ out,
                                             float* __restrict__ srow) {
  __shared__ __align__(16) short As[128 * 32];
  __shared__ __align__(16) short Bs[128 * 32];
  const int tid = threadIdx.x;
  const int w = tid >> 6, l = tid & 63;
  const int wr = w >> 1, wc = w & 1;
  const int bx = blockIdx.x;
  const int row0 = rowBase + blockIdx.y * 128;
  const int col0 = bx * 128;
  const short* Ag = (const short*)A;

  f32x4 acc[4][4];
#pragma unroll
  for (int mi = 0; mi < 4; ++mi)
#pragma unroll
    for (int ni = 0; ni < 4; ++ni) acc[mi][ni] = (f32x4){0.f, 0.f, 0.f, 0.f};

  const int r0 = tid >> 2, s0 = tid & 3;
  const int r1 = (tid + 256) >> 2, s1 = tid & 3;
  const int lrow = l & 15, kb = (l >> 4) * 8;

  for (int k0 = 0; k0 < KK; k0 += 32) {
    __syncthreads();
    gload16(Ag + (size_t)(row0 + r0) * KK + k0 + s0 * 8, &As[tid * 8]);
    gload16(Ag + (size_t)(row0 + r1) * KK + k0 + s1 * 8, &As[(tid + 256) * 8]);
    gload16(Ag + (size_t)(col0 + r0) * KK + k0 + s0 * 8, &Bs[tid * 8]);
    gload16(Ag + (size_t)(col0 + r1) * KK + k0 + s1 * 8, &Bs[(tid + 256) * 8]);
    __syncthreads();
    bf16x8 av[4], bv[4];
#pragma unroll
    for (int mi = 0; mi < 4; ++mi)
      av[mi] = *(const bf16x8*)&As[(wr * 64 + mi * 16 + lrow) * 32 + kb];
#pragma unroll
    for (int ni = 0; ni < 4; ++ni)
      bv[ni] = *(const bf16x8*)&Bs[(wc * 64 + ni * 16 + lrow) * 32 + kb];
#pragma unroll
    for (int mi = 0; mi < 4; ++mi)
#pragma unroll
      for (int ni = 0; ni < 4; ++ni)
        acc[mi][ni] = __builtin_amdgcn_mfma_f32_16x16x32_bf16(av[mi], bv[ni],
                                                              acc[mi][ni], 0, 0, 0);
  }

  const int quad = l >> 4;
#pragma unroll
  for (int mi = 0; mi < 4; ++mi) {
#pragma unroll
    for (int r = 0; r < 4; ++r) {
      const int grow = row0 + wr * 64 + mi * 16 + quad * 4 + r;
      float rsum = 0.f;
#pragma unroll
      for (int ni = 0; ni < 4; ++ni) {
        const int gcol = col0 + wc * 64 + ni * 16 + (l & 15);
        float a = acc[mi][ni][r];
        float s = a / 0.1f;
        out[(size_t)(grow - rowBase) * MM + gcol] = __expf(s);
        rsum += (gcol == grow) ? 0.f : a;
      }
#pragma unroll
      for (int mask = 1; mask < 16; mask <<= 1) rsum += __shfl_xor(rsum, mask, 64);
      if ((l & 15) == 0) srow[(size_t)grow * 64 + bx * 2 + wc] = rsum / 0.1f;
    }
  }
}

// ---------------- per-row loss: merge-path over distance order ----------------
__global__ __launch_bounds__(256) void kloss(const float* __restrict__ expchunk,
                                             int rowBase,
                                             const float* __restrict__ slab_g,
                                             const int* __restrict__ perm_g,
                                             const int* __restrict__ pos_g,
                                             float* __restrict__ part_logd) {
  const int i = rowBase + blockIdx.x;
  const float* row = expchunk + (size_t)blockIdx.x * MM;
  __shared__ float P[PADI(MM) + 1];   // padded exclusive prefix in sorted-label order
  __shared__ float slab[MM];
  __shared__ float wsum[4];
  __shared__ float red[4];
  const int tid = threadIdx.x;
  const int lane = tid & 63, wid = tid >> 6;
  const int m0 = tid * 16;

  for (int d = 0; d < 2; ++d) {
    __syncthreads();   // protect slab/P/red from previous-phase readers
    for (int m = tid; m < MM; m += 256) slab[m] = slab_g[d * MM + m];

    const int pi = pos_g[d * MM + i];

    // gather exp_sims into sorted order (registers)
    float g[16];
    {
      const int4* pm4 = (const int4*)(perm_g + d * MM + m0);
      int idx[16];
#pragma unroll
      for (int q = 0; q < 4; ++q) {
        int4 p4 = pm4[q];
        idx[4 * q + 0] = p4.x; idx[4 * q + 1] = p4.y;
        idx[4 * q + 2] = p4.z; idx[4 * q + 3] = p4.w;
      }
#pragma unroll
      for (int u = 0; u < 16; ++u) g[u] = row[idx[u]];
    }
    float ls = 0.f;
#pragma unroll
    for (int u = 0; u < 16; ++u) ls += g[u];

    // wave-level inclusive scan of per-thread sums
    float v = ls;
#pragma unroll
    for (int s = 1; s < 64; s <<= 1) {
      float t = __shfl_up(v, s, 64);
      if (lane >= s) v += t;
    }
    if (lane == 63) wsum[wid] = v;
    __syncthreads();
    float woff = 0.f;
#pragma unroll
    for (int q = 0; q < 4; ++q) woff += (q < wid) ? wsum[q] : 0.f;
    const float total = wsum[0] + wsum[1] + wsum[2] + wsum[3];
    float run = woff + (v - ls);   // exclusive prefix for this thread's chunk
#pragma unroll
    for (int u = 0; u < 16; ++u) {
      P[PADI(m0 + u)] = run;
      run += g[u];
    }
    if (tid == 0) P[PADI(MM)] = total;
    __syncthreads();

    const float c = slab[pi];
    const float gC = row[i];       // center's exp value (dist == 0 inclusion)

    // ---- merge-path diagonal partition: rank k0r in the distance-merge ----
    const int nB = MM - 1 - pi;
    const int k0r = m0;            // merged-rank start for this thread
    int aLo = k0r - nB; if (aLo < 0) aLo = 0;
    int aHi = (k0r < pi) ? k0r : pi;
    while (aLo < aHi) {
      const int mid = (aLo + aHi) >> 1;
      const float Aa = c - slab[pi - 1 - mid];          // left dist (ascending in mid)
      const float Bb = slab[pi + k0r - mid] - c;        // right dist B[k0r-1-mid]
      if (Aa > Bb) aHi = mid; else aLo = mid + 1;
    }
    int Lp = pi - 1 - aLo;           // next left index to consume
    int Rp = pi + 1 + (k0r - aLo);   // next right index to consume

    float tL = (Lp >= 0) ? (c - slab[Lp]) : INFINITY;
    float tR = (Rp < MM) ? (slab[Rp] - c) : INFINITY;
    float lastLD = -1.f, lastRD = -1.f;
    int lastLo = 0, lastHi = 0;
    float acc = 0.f;
    const int cnt = (MM - 1 - k0r < 16) ? (MM - 1 - k0r) : 16;
    for (int step = 0; step < cnt; ++step) {
      const bool left = (tL <= tR);
      const float t = left ? tL : tR;
      int lo, hi;
      if (left) {                       // consume left element Lp, dist t
        lo = (t == lastLD) ? lastLo : (Lp + 1);
        hi = Rp;
        lastLD = t; lastLo = lo;
      } else {                          // consume right element Rp, dist t
        hi = (t == lastRD) ? lastHi : Rp;
        lo = (t == lastLD) ? lastLo : (Lp + 1);
        lastRD = t; lastHi = hi;
      }
      float denom = P[PADI(lo)] + (total - P[PADI(hi)]) + ((t == 0.f) ? gC : 0.f);
      acc += __logf(fmaxf(denom, 1e-7f));
      if (left) { --Lp; tL = (Lp >= 0) ? (c - slab[Lp]) : INFINITY; }
      else      { ++Rp; tR = (Rp < MM) ? (slab[Rp] - c) : INFINITY; }
    }

    for (int s = 32; s; s >>= 1) acc += __shfl_down(acc, s, 64);
    __syncthreads();
    if ((tid & 63) == 0) red[tid >> 6] = acc;
    __syncthreads();
    if (tid == 0) part_logd[d * MM + i] = red[0] + red[1] + red[2] + red[3];
  }
}

// ---------------- two-stage final reduce (double) ----------------
__global__ __launch_bounds__(256) void kred1(const float* __restrict__ part_logd,
                                             const float* __restrict__ srow,
                                             double* __restrict__ red3) {
  const int tid = threadIdx.x;
  const int base = blockIdx.x * 64;   // 64 rows per block
  double ss = 0.0, s0 = 0.0, s1 = 0.0;
  for (int q = tid; q < 64 * 64; q += 256)
    ss += (double)srow[(size_t)base * 64 + q];
  if (tid < 64) {
    s0 = (double)part_logd[base + tid];
    s1 = (double)part_logd[MM + base + tid];
  }
  for (int s = 32; s; s >>= 1) {
    s0 += __shfl_down(s0, s, 64);
    s1 += __shfl_down(s1, s, 64);
    ss += __shfl_down(ss, s, 64);
  }
  __shared__ double red[3][4];
  if ((tid & 63) == 0) {
    red[0][tid >> 6] = s0; red[1][tid >> 6] = s1; red[2][tid >> 6] = ss;
  }
  __syncthreads();
  if (tid == 0) {
    red3[blockIdx.x * 3 + 0] = red[0][0] + red[0][1] + red[0][2] + red[0][3];
    red3[blockIdx.x * 3 + 1] = red[1][0] + red[1][1] + red[1][2] + red[1][3];
    red3[blockIdx.x * 3 + 2] = red[2][0] + red[2][1] + red[2][2] + red[2][3];
  }
}

__global__ __launch_bounds__(64) void kred2(const double* __restrict__ red3,
                                            float* __restrict__ out) {
  const int t = threadIdx.x;
  double s0 = red3[t * 3 + 0], s1 = red3[t * 3 + 1], ss = red3[t * 3 + 2];
  for (int s = 32; s; s >>= 1) {
    s0 += __shfl_down(s0, s, 64);
    s1 += __shfl_down(s1, s, 64);
    ss += __shfl_down(ss, s, 64);
  }
  if (t == 0) {
    const double n = (double)MM * (double)(MM - 1);
    out[0] = (float)((s0 - ss) / n);
    out[1] = (float)((s1 - ss) / n);
  }
}

extern "C" void kernel_launch(void* const* d_in, const int* in_sizes, int n_in,
                              void* d_out, int out_size, void* d_ws, size_t ws_size,
                              hipStream_t stream) {
  const float* emb = (const float*)d_in[0];
  const float* labels = (const float*)d_in[1];
  float* out = (float*)d_out;
  char* ws = (char*)d_ws;

  size_t off = 0;
  auto alloc = [&](size_t bytes) {
    void* p = ws + off;
    off = (off + bytes + 255) & ~(size_t)255;
    return p;
  };
  __hip_bfloat16* nb = (__hip_bfloat16*)alloc((size_t)MM * KK * 2);
  float* slab = (float*)alloc((size_t)2 * MM * 4);
  int* perm = (int*)alloc((size_t)2 * MM * 4);
  int* pos = (int*)alloc((size_t)2 * MM * 4);
  int* rank = (int*)alloc((size_t)2 * MM * 4);
  float* part_logd = (float*)alloc((size_t)2 * MM * 4);
  float* srow = (float*)alloc((size_t)MM * 64 * 4);
  double* red3 = (double*)alloc((size_t)64 * 3 * 8);
  size_t fixed = off;

  size_t avail = (ws_size > fixed) ? (ws_size - fixed) : 0;
  long long cr = (long long)(avail / ((size_t)MM * 4));
  cr = (cr / 128) * 128;
  if (cr > MM) cr = MM;
  if (cr < 128) cr = 128;
  int chunk_rows = (int)cr;
  float* expchunk = (float*)(ws + fixed);

  knorm<<<MM, 256, 0, stream>>>(emb, nb);
  hipMemsetAsync(rank, 0, (size_t)2 * MM * 4, stream);
  krank<<<dim3(16, 16, 2), 256, 0, stream>>>(labels, rank);
  kscatter<<<32, 256, 0, stream>>>(labels, rank, slab, perm, pos);

  for (int base = 0; base < MM; base += chunk_rows) {
    int rows = MM - base < chunk_rows ? MM - base : chunk_rows;
    kgemm<<<dim3(MM / 128, rows / 128), 256, 0, stream>>>(nb, base, expchunk, srow);
    kloss<<<rows, 256, 0, stream>>>(expchunk, base, slab, perm, pos, part_logd);
  }
  kred1<<<64, 256, 0, stream>>>(part_logd, srow, red3);
  kred2<<<1, 64, 0, stream>>>(red3, out);
}

// Round 7
// 155.632 us; speedup vs baseline: 9.4851x; 1.0535x over previous
//
#include <hip/hip_runtime.h>
#include <hip/hip_bf16.h>
#include <math.h>

#define MM 4096
#define KK 768
#define NB (MM / 128)
#define PADI(m) ((m) + ((m) >> 4))

typedef short bf16x8 __attribute__((ext_vector_type(8)));
typedef float f32x4 __attribute__((ext_vector_type(4)));

__device__ __forceinline__ void gload16(const void* g, void* l) {
#if __has_builtin(__builtin_amdgcn_global_load_lds)
  __builtin_amdgcn_global_load_lds((__attribute__((address_space(1))) void*)g,
                                   (__attribute__((address_space(3))) void*)l,
                                   16, 0, 0);
#else
  *(bf16x8*)l = *(const bf16x8*)g;
#endif
}

// ---------------- normalize rows -> bf16 ----------------
__global__ __launch_bounds__(256) void knorm(const float* __restrict__ emb,
                                             __hip_bfloat16* __restrict__ nb) {
  int row = blockIdx.x;
  int tid = threadIdx.x;
  const float* e = emb + (size_t)row * KK;
  float v0 = e[tid], v1 = e[tid + 256], v2 = e[tid + 512];
  float ss = v0 * v0 + v1 * v1 + v2 * v2;
  for (int s = 32; s; s >>= 1) ss += __shfl_down(ss, s, 64);
  __shared__ float red[4];
  if ((tid & 63) == 0) red[tid >> 6] = ss;
  __syncthreads();
  float tot = red[0] + red[1] + red[2] + red[3];
  float inv = 1.f / fmaxf(sqrtf(tot), 1e-12f);
  __hip_bfloat16* o = nb + (size_t)row * KK;
  o[tid] = __float2bfloat16(v0 * inv);
  o[tid + 256] = __float2bfloat16(v1 * inv);
  o[tid + 512] = __float2bfloat16(v2 * inv);
}

// ---------------- rank labels: 256x256 tiles ----------------
__global__ __launch_bounds__(256) void krank(const float* __restrict__ labels,
                                             int* __restrict__ rank) {
  __shared__ float lab[256];
  const int slice = blockIdx.x, chunk = blockIdx.y, d = blockIdx.z;
  const int tid = threadIdx.x;
  const int kg0 = chunk * 256;
  lab[tid] = labels[(size_t)(kg0 + tid) * 2 + d];
  const int i = slice * 256 + tid;
  const float v = labels[(size_t)i * 2 + d];
  __syncthreads();
  int r = 0;
#pragma unroll 8
  for (int k = 0; k < 256; ++k) {
    const float w = lab[k];
    r += (w < v) || (w == v && (kg0 + k) < i);
  }
  atomicAdd(&rank[d * MM + i], r);
}

__global__ __launch_bounds__(256) void kscatter(const float* __restrict__ labels,
                                                const int* __restrict__ rank,
                                                float* __restrict__ slab,
                                                int* __restrict__ perm,
                                                int* __restrict__ pos) {
  const int d = blockIdx.x >> 4;
  const int i = (blockIdx.x & 15) * 256 + threadIdx.x;
  const int r = rank[d * MM + i];
  slab[d * MM + r] = labels[(size_t)i * 2 + d];
  perm[d * MM + r] = i;
  pos[d * MM + i] = r;
}

// ---------------- symmetric bf16 MFMA GEMM (upper-triangle blocks) ----------------
union SmemU {
  struct { short As[128 * 32]; short Bs[128 * 32]; } s;
  float tbuf[32][133];
};

__global__ __launch_bounds__(256) void kgemm_sym(const __hip_bfloat16* __restrict__ A,
                                                 float* __restrict__ out,
                                                 float* __restrict__ srow) {
  __shared__ __align__(16) SmemU sm;
  const int tid = threadIdx.x;
  const int w = tid >> 6, l = tid & 63;
  const int wr = w >> 1, wc = w & 1;
  // decode triangular block index -> (by, bx) with bx >= by
  int b = blockIdx.x, by = 0;
  while (b >= NB - by) { b -= NB - by; ++by; }
  const int bx = by + b;
  const int row0 = by * 128, col0 = bx * 128;
  const short* Ag = (const short*)A;

  f32x4 acc[4][4];
#pragma unroll
  for (int mi = 0; mi < 4; ++mi)
#pragma unroll
    for (int ni = 0; ni < 4; ++ni) acc[mi][ni] = (f32x4){0.f, 0.f, 0.f, 0.f};

  const int r0 = tid >> 2, s0 = tid & 3;
  const int r1 = (tid + 256) >> 2;
  const int lrow = l & 15, kb = (l >> 4) * 8;

  for (int k0 = 0; k0 < KK; k0 += 32) {
    __syncthreads();
    gload16(Ag + (size_t)(row0 + r0) * KK + k0 + s0 * 8, &sm.s.As[tid * 8]);
    gload16(Ag + (size_t)(row0 + r1) * KK + k0 + s0 * 8, &sm.s.As[(tid + 256) * 8]);
    gload16(Ag + (size_t)(col0 + r0) * KK + k0 + s0 * 8, &sm.s.Bs[tid * 8]);
    gload16(Ag + (size_t)(col0 + r1) * KK + k0 + s0 * 8, &sm.s.Bs[(tid + 256) * 8]);
    __syncthreads();
    bf16x8 av[4], bv[4];
#pragma unroll
    for (int mi = 0; mi < 4; ++mi)
      av[mi] = *(const bf16x8*)&sm.s.As[(wr * 64 + mi * 16 + lrow) * 32 + kb];
#pragma unroll
    for (int ni = 0; ni < 4; ++ni)
      bv[ni] = *(const bf16x8*)&sm.s.Bs[(wc * 64 + ni * 16 + lrow) * 32 + kb];
#pragma unroll
    for (int mi = 0; mi < 4; ++mi)
#pragma unroll
      for (int ni = 0; ni < 4; ++ni)
        acc[mi][ni] = __builtin_amdgcn_mfma_f32_16x16x32_bf16(av[mi], bv[ni],
                                                              acc[mi][ni], 0, 0, 0);
  }

  const int quad = l >> 4;
  const bool diag = (bx == by);

  // normal row-sums: slot bx*2 + wc
#pragma unroll
  for (int mi = 0; mi < 4; ++mi) {
#pragma unroll
    for (int r = 0; r < 4; ++r) {
      const int grow = row0 + wr * 64 + mi * 16 + quad * 4 + r;
      float rsum = 0.f;
#pragma unroll
      for (int ni = 0; ni < 4; ++ni) {
        const int gcol = col0 + wc * 64 + ni * 16 + (l & 15);
        rsum += (diag && gcol == grow) ? 0.f : acc[mi][ni][r];
      }
#pragma unroll
      for (int mask = 1; mask < 16; mask <<= 1) rsum += __shfl_xor(rsum, mask, 64);
      if ((l & 15) == 0) srow[(size_t)grow * 64 + bx * 2 + wc] = rsum / 0.1f;
    }
  }

  // mirrored row-sums = tile column sums: slot by*2 + wr
  if (!diag) {
#pragma unroll
    for (int ni = 0; ni < 4; ++ni) {
      float csum = 0.f;
#pragma unroll
      for (int mi = 0; mi < 4; ++mi)
#pragma unroll
        for (int r = 0; r < 4; ++r) csum += acc[mi][ni][r];
      csum += __shfl_xor(csum, 16, 64);
      csum += __shfl_xor(csum, 32, 64);
      if (quad == 0)
        srow[(size_t)(col0 + wc * 64 + ni * 16 + l) * 64 + by * 2 + wr] = csum / 0.1f;
    }
  }

  // exp in place
#pragma unroll
  for (int mi = 0; mi < 4; ++mi)
#pragma unroll
    for (int ni = 0; ni < 4; ++ni)
#pragma unroll
      for (int r = 0; r < 4; ++r)
        acc[mi][ni][r] = __expf(acc[mi][ni][r] / 0.1f);

  // normal store
#pragma unroll
  for (int mi = 0; mi < 4; ++mi)
#pragma unroll
    for (int r = 0; r < 4; ++r) {
      const int grow = row0 + wr * 64 + mi * 16 + quad * 4 + r;
#pragma unroll
      for (int ni = 0; ni < 4; ++ni)
        out[(size_t)grow * MM + col0 + wc * 64 + ni * 16 + (l & 15)] = acc[mi][ni][r];
    }

  // mirrored (transposed) store via LDS, 4 passes of 32 transposed-rows
  if (!diag) {
#pragma unroll
    for (int p = 0; p < 4; ++p) {
      const int pwc = p >> 1, pni0 = (p & 1) * 2;
      __syncthreads();
      if (wc == pwc) {
#pragma unroll
        for (int nn = 0; nn < 2; ++nn) {
          const int ni = pni0 + nn;
          const int ltr = nn * 16 + (l & 15);
#pragma unroll
          for (int mi = 0; mi < 4; ++mi) {
            const int cbase = wr * 64 + mi * 16 + quad * 4;
#pragma unroll
            for (int r = 0; r < 4; ++r)
              sm.tbuf[ltr][cbase + r] = acc[mi][ni][r];
          }
        }
      }
      __syncthreads();
      const int trow = tid >> 3;
      const int cseg = (tid & 7) * 16;
      const int gtr = col0 + p * 32 + trow;   // global row of mirrored tile
      float v[16];
#pragma unroll
      for (int q = 0; q < 16; ++q) v[q] = sm.tbuf[trow][cseg + q];
      float* dst = out + (size_t)gtr * MM + row0 + cseg;
#pragma unroll
      for (int q = 0; q < 4; ++q)
        *(float4*)(dst + q * 4) = (float4){v[4 * q], v[4 * q + 1], v[4 * q + 2], v[4 * q + 3]};
    }
  }
}

// ---------------- chunked fallback GEMM (used only if workspace is small) ----------
__global__ __launch_bounds__(256) void kgemm(const __hip_bfloat16* __restrict__ A,
                                             int rowBase,
                                             float* __restrict__ out,
                                             float* __restrict__ srow) {
  __shared__ __align__(16) short As[128 * 32];
  __shared__ __align__(16) short Bs[128 * 32];
  const int tid = threadIdx.x;
  const int w = tid >> 6, l = tid & 63;
  const int wr = w >> 1, wc = w & 1;
  const int bx = blockIdx.x;
  const int row0 = rowBase + blockIdx.y * 128;
  const int col0 = bx * 128;
  const short* Ag = (const short*)A;

  f32x4 acc[4][4];
#pragma unroll
  for (int mi = 0; mi < 4; ++mi)
#pragma unroll
    for (int ni = 0; ni < 4; ++ni) acc[mi][ni] = (f32x4){0.f, 0.f, 0.f, 0.f};

  const int r0 = tid >> 2, s0 = tid & 3;
  const int r1 = (tid + 256) >> 2;
  const int lrow = l & 15, kb = (l >> 4) * 8;

  for (int k0 = 0; k0 < KK; k0 += 32) {
    __syncthreads();
    gload16(Ag + (size_t)(row0 + r0) * KK + k0 + s0 * 8, &As[tid * 8]);
    gload16(Ag + (size_t)(row0 + r1) * KK + k0 + s0 * 8, &As[(tid + 256) * 8]);
    gload16(Ag + (size_t)(col0 + r0) * KK + k0 + s0 * 8, &Bs[tid * 8]);
    gload16(Ag + (size_t)(col0 + r1) * KK + k0 + s0 * 8, &Bs[(tid + 256) * 8]);
    __syncthreads();
    bf16x8 av[4], bv[4];
#pragma unroll
    for (int mi = 0; mi < 4; ++mi)
      av[mi] = *(const bf16x8*)&As[(wr * 64 + mi * 16 + lrow) * 32 + kb];
#pragma unroll
    for (int ni = 0; ni < 4; ++ni)
      bv[ni] = *(const bf16x8*)&Bs[(wc * 64 + ni * 16 + lrow) * 32 + kb];
#pragma unroll
    for (int mi = 0; mi < 4; ++mi)
#pragma unroll
      for (int ni = 0; ni < 4; ++ni)
        acc[mi][ni] = __builtin_amdgcn_mfma_f32_16x16x32_bf16(av[mi], bv[ni],
                                                              acc[mi][ni], 0, 0, 0);
  }

  const int quad = l >> 4;
#pragma unroll
  for (int mi = 0; mi < 4; ++mi) {
#pragma unroll
    for (int r = 0; r < 4; ++r) {
      const int grow = row0 + wr * 64 + mi * 16 + quad * 4 + r;
      float rsum = 0.f;
#pragma unroll
      for (int ni = 0; ni < 4; ++ni) {
        const int gcol = col0 + wc * 64 + ni * 16 + (l & 15);
        float a = acc[mi][ni][r];
        out[(size_t)(grow - rowBase) * MM + gcol] = __expf(a / 0.1f);
        rsum += (gcol == grow) ? 0.f : a;
      }
#pragma unroll
      for (int mask = 1; mask < 16; mask <<= 1) rsum += __shfl_xor(rsum, mask, 64);
      if ((l & 15) == 0) srow[(size_t)grow * 64 + bx * 2 + wc] = rsum / 0.1f;
    }
  }
}

// ---------------- per-row loss: branch-free pipelined merge ----------------
__global__ __launch_bounds__(256) void kloss(const float* __restrict__ expchunk,
                                             int rowBase,
                                             const float* __restrict__ slab_g,
                                             const int* __restrict__ perm_g,
                                             const int* __restrict__ pos_g,
                                             float* __restrict__ part_logd) {
  const int i = rowBase + blockIdx.x;
  const float* row = expchunk + (size_t)blockIdx.x * MM;
  __shared__ float P[PADI(MM) + 1];
  __shared__ __align__(16) float slab[MM];
  __shared__ float wsum[4];
  __shared__ float red[4];
  const int tid = threadIdx.x;
  const int lane = tid & 63, wid = tid >> 6;
  const int m0 = tid * 16;

  for (int d = 0; d < 2; ++d) {
    __syncthreads();
    for (int q = tid; q < MM / 4; q += 256)
      ((float4*)slab)[q] = ((const float4*)(slab_g + (size_t)d * MM))[q];

    const int pi = pos_g[d * MM + i];

    // gather exp_sims into sorted order (registers)
    float g[16];
    {
      const int4* pm4 = (const int4*)(perm_g + d * MM + m0);
      int idx[16];
#pragma unroll
      for (int q = 0; q < 4; ++q) {
        int4 p4 = pm4[q];
        idx[4 * q + 0] = p4.x; idx[4 * q + 1] = p4.y;
        idx[4 * q + 2] = p4.z; idx[4 * q + 3] = p4.w;
      }
#pragma unroll
      for (int u = 0; u < 16; ++u) g[u] = row[idx[u]];
    }
    float ls = 0.f;
#pragma unroll
    for (int u = 0; u < 16; ++u) ls += g[u];

    // wave-level inclusive scan of per-thread sums
    float v = ls;
#pragma unroll
    for (int s = 1; s < 64; s <<= 1) {
      float t = __shfl_up(v, s, 64);
      if (lane >= s) v += t;
    }
    if (lane == 63) wsum[wid] = v;
    __syncthreads();
    float woff = 0.f;
#pragma unroll
    for (int q = 0; q < 4; ++q) woff += (q < wid) ? wsum[q] : 0.f;
    const float total = wsum[0] + wsum[1] + wsum[2] + wsum[3];
    float run = woff + (v - ls);
#pragma unroll
    for (int u = 0; u < 16; ++u) {
      P[PADI(m0 + u)] = run;
      run += g[u];
    }
    if (tid == 0) P[PADI(MM)] = total;
    __syncthreads();

    const float c = slab[pi];
    const float gC = row[i];

    // merge-path diagonal partition
    const int nB2 = MM - 1 - pi;
    const int k0r = m0;
    int aLo = k0r - nB2; if (aLo < 0) aLo = 0;
    int aHi = (k0r < pi) ? k0r : pi;
    while (aLo < aHi) {
      const int mid = (aLo + aHi) >> 1;
      const float Aa = c - slab[pi - 1 - mid];
      const float Bb = slab[pi + k0r - mid] - c;
      if (Aa > Bb) aHi = mid; else aLo = mid + 1;
    }
    int Lp = pi - 1 - aLo;
    int Rp = pi + 1 + (k0r - aLo);

    float tL = (Lp >= 0) ? (c - slab[Lp]) : INFINITY;
    float tR = (Rp < MM) ? (slab[Rp] - c) : INFINITY;
    // depth-1 prefetch of next candidates
    float nL = slab[max(Lp - 1, 0)];
    float nR = slab[min(Rp + 1, MM - 1)];
    float lastLD = -1.f, lastRD = -1.f;
    int lastLo = 0, lastHi = 0;
    float mprod = 1.f;
    int esum = 0;
    const int cnt = (MM - 1 - k0r < 16) ? (MM - 1 - k0r) : 16;
    for (int step = 0; step < cnt; ++step) {
      const bool left = (tL <= tR);
      const float t = left ? tL : tR;
      const int lo = (t == lastLD) ? lastLo : (Lp + 1);
      const int hi = (!left && t == lastRD) ? lastHi : Rp;
      lastLD = left ? t : lastLD;
      lastLo = left ? lo : lastLo;
      lastRD = left ? lastRD : t;
      lastHi = left ? lastHi : hi;
      float denom = P[PADI(lo)] + (total - P[PADI(hi)]) + ((t == 0.f) ? gC : 0.f);
      denom = fmaxf(denom, 1e-7f);
      int ex;
      const float mant = frexpf(denom, &ex);
      mprod *= mant;
      esum += ex;
      Lp -= left ? 1 : 0;
      Rp += left ? 0 : 1;
      tL = left ? ((Lp >= 0) ? (c - nL) : INFINITY) : tL;
      tR = left ? tR : ((Rp < MM) ? (nR - c) : INFINITY);
      const int pa = left ? (Lp - 1) : (Rp + 1);
      const int pac = min(max(pa, 0), MM - 1);
      const float pv = slab[pac];
      nL = left ? pv : nL;
      nR = left ? nR : pv;
    }
    float acc = __logf(mprod) + (float)esum * 0.6931471805599453f;

    for (int s = 32; s; s >>= 1) acc += __shfl_down(acc, s, 64);
    __syncthreads();
    if ((tid & 63) == 0) red[tid >> 6] = acc;
    __syncthreads();
    if (tid == 0) part_logd[d * MM + i] = red[0] + red[1] + red[2] + red[3];
  }
}

// ---------------- two-stage final reduce (double) ----------------
__global__ __launch_bounds__(256) void kred1(const float* __restrict__ part_logd,
                                             const float* __restrict__ srow,
                                             double* __restrict__ red3) {
  const int tid = threadIdx.x;
  const int base = blockIdx.x * 64;
  double ss = 0.0, s0 = 0.0, s1 = 0.0;
  for (int q = tid; q < 64 * 64; q += 256)
    ss += (double)srow[(size_t)base * 64 + q];
  if (tid < 64) {
    s0 = (double)part_logd[base + tid];
    s1 = (double)part_logd[MM + base + tid];
  }
  for (int s = 32; s; s >>= 1) {
    s0 += __shfl_down(s0, s, 64);
    s1 += __shfl_down(s1, s, 64);
    ss += __shfl_down(ss, s, 64);
  }
  __shared__ double red[3][4];
  if ((tid & 63) == 0) {
    red[0][tid >> 6] = s0; red[1][tid >> 6] = s1; red[2][tid >> 6] = ss;
  }
  __syncthreads();
  if (tid == 0) {
    red3[blockIdx.x * 3 + 0] = red[0][0] + red[0][1] + red[0][2] + red[0][3];
    red3[blockIdx.x * 3 + 1] = red[1][0] + red[1][1] + red[1][2] + red[1][3];
    red3[blockIdx.x * 3 + 2] = red[2][0] + red[2][1] + red[2][2] + red[2][3];
  }
}

__global__ __launch_bounds__(64) void kred2(const double* __restrict__ red3,
                                            float* __restrict__ out) {
  const int t = threadIdx.x;
  double s0 = red3[t * 3 + 0], s1 = red3[t * 3 + 1], ss = red3[t * 3 + 2];
  for (int s = 32; s; s >>= 1) {
    s0 += __shfl_down(s0, s, 64);
    s1 += __shfl_down(s1, s, 64);
    ss += __shfl_down(ss, s, 64);
  }
  if (t == 0) {
    const double n = (double)MM * (double)(MM - 1);
    out[0] = (float)((s0 - ss) / n);
    out[1] = (float)((s1 - ss) / n);
  }
}

extern "C" void kernel_launch(void* const* d_in, const int* in_sizes, int n_in,
                              void* d_out, int out_size, void* d_ws, size_t ws_size,
                              hipStream_t stream) {
  const float* emb = (const float*)d_in[0];
  const float* labels = (const float*)d_in[1];
  float* out = (float*)d_out;
  char* ws = (char*)d_ws;

  size_t off = 0;
  auto alloc = [&](size_t bytes) {
    void* p = ws + off;
    off = (off + bytes + 255) & ~(size_t)255;
    return p;
  };
  __hip_bfloat16* nb = (__hip_bfloat16*)alloc((size_t)MM * KK * 2);
  float* slab = (float*)alloc((size_t)2 * MM * 4);
  int* perm = (int*)alloc((size_t)2 * MM * 4);
  int* pos = (int*)alloc((size_t)2 * MM * 4);
  int* rank = (int*)alloc((size_t)2 * MM * 4);
  float* part_logd = (float*)alloc((size_t)2 * MM * 4);
  float* srow = (float*)alloc((size_t)MM * 64 * 4);
  double* red3 = (double*)alloc((size_t)64 * 3 * 8);
  size_t fixed = off;

  size_t avail = (ws_size > fixed) ? (ws_size - fixed) : 0;
  long long cr = (long long)(avail / ((size_t)MM * 4));
  cr = (cr / 128) * 128;
  if (cr > MM) cr = MM;
  if (cr < 128) cr = 128;
  int chunk_rows = (int)cr;
  float* expchunk = (float*)(ws + fixed);

  knorm<<<MM, 256, 0, stream>>>(emb, nb);
  hipMemsetAsync(rank, 0, (size_t)2 * MM * 4, stream);
  krank<<<dim3(16, 16, 2), 256, 0, stream>>>(labels, rank);
  kscatter<<<32, 256, 0, stream>>>(labels, rank, slab, perm, pos);

  if (chunk_rows == MM) {
    kgemm_sym<<<NB * (NB + 1) / 2, 256, 0, stream>>>(nb, expchunk, srow);
    kloss<<<MM, 256, 0, stream>>>(expchunk, 0, slab, perm, pos, part_logd);
  } else {
    for (int base = 0; base < MM; base += chunk_rows) {
      int rows = MM - base < chunk_rows ? MM - base : chunk_rows;
      kgemm<<<dim3(MM / 128, rows / 128), 256, 0, stream>>>(nb, base, expchunk, srow);
      kloss<<<rows, 256, 0, stream>>>(expchunk, base, slab, perm, pos, part_logd);
    }
  }
  kred1<<<64, 256, 0, stream>>>(part_logd, srow, red3);
  kred2<<<1, 64, 0, stream>>>(red3, out);
}

// Round 8
// 149.322 us; speedup vs baseline: 9.8859x; 1.0423x over previous
//
#include <hip/hip_runtime.h>
#include <hip/hip_bf16.h>
#include <math.h>

#define MM 4096
#define KK 768
#define NB64 64
#define PADI(m) ((m) + ((m) >> 4))

typedef short bf16x8 __attribute__((ext_vector_type(8)));
typedef float f32x4 __attribute__((ext_vector_type(4)));

__device__ __forceinline__ void gload16(const void* g, void* l) {
#if __has_builtin(__builtin_amdgcn_global_load_lds)
  __builtin_amdgcn_global_load_lds((__attribute__((address_space(1))) void*)g,
                                   (__attribute__((address_space(3))) void*)l,
                                   16, 0, 0);
#else
  *(bf16x8*)l = *(const bf16x8*)g;
#endif
}

// ---------------- normalize rows -> bf16 ----------------
__global__ __launch_bounds__(256) void knorm(const float* __restrict__ emb,
                                             __hip_bfloat16* __restrict__ nb) {
  int row = blockIdx.x;
  int tid = threadIdx.x;
  const float* e = emb + (size_t)row * KK;
  float v0 = e[tid], v1 = e[tid + 256], v2 = e[tid + 512];
  float ss = v0 * v0 + v1 * v1 + v2 * v2;
  for (int s = 32; s; s >>= 1) ss += __shfl_down(ss, s, 64);
  __shared__ float red[4];
  if ((tid & 63) == 0) red[tid >> 6] = ss;
  __syncthreads();
  float tot = red[0] + red[1] + red[2] + red[3];
  float inv = 1.f / fmaxf(sqrtf(tot), 1e-12f);
  __hip_bfloat16* o = nb + (size_t)row * KK;
  o[tid] = __float2bfloat16(v0 * inv);
  o[tid + 256] = __float2bfloat16(v1 * inv);
  o[tid + 512] = __float2bfloat16(v2 * inv);
}

// ---------------- rank labels: 256x256 tiles ----------------
__global__ __launch_bounds__(256) void krank(const float* __restrict__ labels,
                                             int* __restrict__ rank) {
  __shared__ float lab[256];
  const int slice = blockIdx.x, chunk = blockIdx.y, d = blockIdx.z;
  const int tid = threadIdx.x;
  const int kg0 = chunk * 256;
  lab[tid] = labels[(size_t)(kg0 + tid) * 2 + d];
  const int i = slice * 256 + tid;
  const float v = labels[(size_t)i * 2 + d];
  __syncthreads();
  int r = 0;
#pragma unroll 8
  for (int k = 0; k < 256; ++k) {
    const float w = lab[k];
    r += (w < v) || (w == v && (kg0 + k) < i);
  }
  atomicAdd(&rank[d * MM + i], r);
}

__global__ __launch_bounds__(256) void kscatter(const float* __restrict__ labels,
                                                const int* __restrict__ rank,
                                                float* __restrict__ slab,
                                                int* __restrict__ perm,
                                                int* __restrict__ pos) {
  const int d = blockIdx.x >> 4;
  const int i = (blockIdx.x & 15) * 256 + threadIdx.x;
  const int r = rank[d * MM + i];
  slab[d * MM + r] = labels[(size_t)i * 2 + d];
  perm[d * MM + r] = i;
  pos[d * MM + i] = r;
}

// ---------------- symmetric bf16 MFMA GEMM, 64x64 tiles (2080 blocks) ----------------
union SmemU64 {
  struct { short As[64 * 32]; short Bs[64 * 32]; } s;
  float tbuf[32][68];
};

__global__ __launch_bounds__(256) void kgemm_sym64(const __hip_bfloat16* __restrict__ A,
                                                   float* __restrict__ out,
                                                   float* __restrict__ srow) {
  __shared__ __align__(16) SmemU64 sm;
  const int tid = threadIdx.x;
  const int w = tid >> 6, l = tid & 63;
  const int wr = w >> 1, wc = w & 1;
  // decode triangular block index -> (by, bx), bx >= by
  const int b = blockIdx.x;
  int by = (int)((129.0f - sqrtf(16641.0f - 8.0f * (float)b)) * 0.5f);
  by = min(max(by, 0), 63);
  while (by > 0 && (by * (129 - by)) / 2 > b) --by;
  while (by < 63 && (((by + 1) * (129 - (by + 1))) / 2) <= b) ++by;
  const int bx = by + (b - (by * (129 - by)) / 2);
  const int row0 = by * 64, col0 = bx * 64;
  const short* Ag = (const short*)A;

  f32x4 acc[2][2];
#pragma unroll
  for (int mi = 0; mi < 2; ++mi)
#pragma unroll
    for (int ni = 0; ni < 2; ++ni) acc[mi][ni] = (f32x4){0.f, 0.f, 0.f, 0.f};

  const int r0 = tid >> 2, s0 = tid & 3;
  const int lrow = l & 15, kb = (l >> 4) * 8;

  for (int k0 = 0; k0 < KK; k0 += 32) {
    __syncthreads();
    gload16(Ag + (size_t)(row0 + r0) * KK + k0 + s0 * 8, &sm.s.As[tid * 8]);
    gload16(Ag + (size_t)(col0 + r0) * KK + k0 + s0 * 8, &sm.s.Bs[tid * 8]);
    __syncthreads();
    bf16x8 av[2], bv[2];
#pragma unroll
    for (int mi = 0; mi < 2; ++mi)
      av[mi] = *(const bf16x8*)&sm.s.As[(wr * 32 + mi * 16 + lrow) * 32 + kb];
#pragma unroll
    for (int ni = 0; ni < 2; ++ni)
      bv[ni] = *(const bf16x8*)&sm.s.Bs[(wc * 32 + ni * 16 + lrow) * 32 + kb];
#pragma unroll
    for (int mi = 0; mi < 2; ++mi)
#pragma unroll
      for (int ni = 0; ni < 2; ++ni)
        acc[mi][ni] = __builtin_amdgcn_mfma_f32_16x16x32_bf16(av[mi], bv[ni],
                                                              acc[mi][ni], 0, 0, 0);
  }

  const int quad = l >> 4;
  const bool diag = (bx == by);

  // normal row-sums: slot bx*2 + wc (128-slot srow)
#pragma unroll
  for (int mi = 0; mi < 2; ++mi) {
#pragma unroll
    for (int r = 0; r < 4; ++r) {
      const int grow = row0 + wr * 32 + mi * 16 + quad * 4 + r;
      float rsum = 0.f;
#pragma unroll
      for (int ni = 0; ni < 2; ++ni) {
        const int gcol = col0 + wc * 32 + ni * 16 + lrow;
        rsum += (diag && gcol == grow) ? 0.f : acc[mi][ni][r];
      }
#pragma unroll
      for (int mask = 1; mask < 16; mask <<= 1) rsum += __shfl_xor(rsum, mask, 64);
      if (lrow == 0) srow[(size_t)grow * 128 + bx * 2 + wc] = rsum / 0.1f;
    }
  }

  // mirrored row-sums = tile column sums: slot by*2 + wr
  if (!diag) {
#pragma unroll
    for (int ni = 0; ni < 2; ++ni) {
      float csum = 0.f;
#pragma unroll
      for (int mi = 0; mi < 2; ++mi)
#pragma unroll
        for (int r = 0; r < 4; ++r) csum += acc[mi][ni][r];
      csum += __shfl_xor(csum, 16, 64);
      csum += __shfl_xor(csum, 32, 64);
      if (quad == 0)
        srow[(size_t)(col0 + wc * 32 + ni * 16 + l) * 128 + by * 2 + wr] = csum / 0.1f;
    }
  }

  // exp in place
#pragma unroll
  for (int mi = 0; mi < 2; ++mi)
#pragma unroll
    for (int ni = 0; ni < 2; ++ni)
#pragma unroll
      for (int r = 0; r < 4; ++r)
        acc[mi][ni][r] = __expf(acc[mi][ni][r] / 0.1f);

  // normal store
#pragma unroll
  for (int mi = 0; mi < 2; ++mi)
#pragma unroll
    for (int r = 0; r < 4; ++r) {
      const int grow = row0 + wr * 32 + mi * 16 + quad * 4 + r;
#pragma unroll
      for (int ni = 0; ni < 2; ++ni)
        out[(size_t)grow * MM + col0 + wc * 32 + ni * 16 + lrow] = acc[mi][ni][r];
    }

  // mirrored (transposed) store via LDS, 2 passes of 32 transposed-rows
  if (!diag) {
#pragma unroll
    for (int p = 0; p < 2; ++p) {
      __syncthreads();
      if (wc == p) {
#pragma unroll
        for (int ni = 0; ni < 2; ++ni) {
          const int ltr = ni * 16 + lrow;
#pragma unroll
          for (int mi = 0; mi < 2; ++mi) {
            const int cbase = wr * 32 + mi * 16 + quad * 4;
#pragma unroll
            for (int r = 0; r < 4; ++r)
              sm.tbuf[ltr][cbase + r] = acc[mi][ni][r];
          }
        }
      }
      __syncthreads();
      const int trow = tid >> 3;
      const int cseg = (tid & 7) * 8;
      const int gtr = col0 + p * 32 + trow;
      float v[8];
#pragma unroll
      for (int q = 0; q < 8; ++q) v[q] = sm.tbuf[trow][cseg + q];
      float* dst = out + (size_t)gtr * MM + row0 + cseg;
      *(float4*)(dst) = (float4){v[0], v[1], v[2], v[3]};
      *(float4*)(dst + 4) = (float4){v[4], v[5], v[6], v[7]};
    }
  }
}

// ---------------- chunked fallback GEMM (small workspace only) ----------
__global__ __launch_bounds__(256) void kgemm(const __hip_bfloat16* __restrict__ A,
                                             int rowBase,
                                             float* __restrict__ out,
                                             float* __restrict__ srow) {
  __shared__ __align__(16) short As[128 * 32];
  __shared__ __align__(16) short Bs[128 * 32];
  const int tid = threadIdx.x;
  const int w = tid >> 6, l = tid & 63;
  const int wr = w >> 1, wc = w & 1;
  const int bx = blockIdx.x;
  const int row0 = rowBase + blockIdx.y * 128;
  const int col0 = bx * 128;
  const short* Ag = (const short*)A;

  f32x4 acc[4][4];
#pragma unroll
  for (int mi = 0; mi < 4; ++mi)
#pragma unroll
    for (int ni = 0; ni < 4; ++ni) acc[mi][ni] = (f32x4){0.f, 0.f, 0.f, 0.f};

  const int r0 = tid >> 2, s0 = tid & 3;
  const int r1 = (tid + 256) >> 2;
  const int lrow = l & 15, kb = (l >> 4) * 8;

  for (int k0 = 0; k0 < KK; k0 += 32) {
    __syncthreads();
    gload16(Ag + (size_t)(row0 + r0) * KK + k0 + s0 * 8, &As[tid * 8]);
    gload16(Ag + (size_t)(row0 + r1) * KK + k0 + s0 * 8, &As[(tid + 256) * 8]);
    gload16(Ag + (size_t)(col0 + r0) * KK + k0 + s0 * 8, &Bs[tid * 8]);
    gload16(Ag + (size_t)(col0 + r1) * KK + k0 + s0 * 8, &Bs[(tid + 256) * 8]);
    __syncthreads();
    bf16x8 av[4], bv[4];
#pragma unroll
    for (int mi = 0; mi < 4; ++mi)
      av[mi] = *(const bf16x8*)&As[(wr * 64 + mi * 16 + lrow) * 32 + kb];
#pragma unroll
    for (int ni = 0; ni < 4; ++ni)
      bv[ni] = *(const bf16x8*)&Bs[(wc * 64 + ni * 16 + lrow) * 32 + kb];
#pragma unroll
    for (int mi = 0; mi < 4; ++mi)
#pragma unroll
      for (int ni = 0; ni < 4; ++ni)
        acc[mi][ni] = __builtin_amdgcn_mfma_f32_16x16x32_bf16(av[mi], bv[ni],
                                                              acc[mi][ni], 0, 0, 0);
  }

  const int quad = l >> 4;
#pragma unroll
  for (int mi = 0; mi < 4; ++mi) {
#pragma unroll
    for (int r = 0; r < 4; ++r) {
      const int grow = row0 + wr * 64 + mi * 16 + quad * 4 + r;
      float rsum = 0.f;
#pragma unroll
      for (int ni = 0; ni < 4; ++ni) {
        const int gcol = col0 + wc * 64 + ni * 16 + lrow;
        float a = acc[mi][ni][r];
        out[(size_t)(grow - rowBase) * MM + gcol] = __expf(a / 0.1f);
        rsum += (gcol == grow) ? 0.f : a;
      }
#pragma unroll
      for (int mask = 1; mask < 16; mask <<= 1) rsum += __shfl_xor(rsum, mask, 64);
      if (lrow == 0) srow[(size_t)grow * 128 + bx * 2 + wc] = rsum / 0.1f;
    }
  }
}

// ---------------- per-row loss: CS-merge over distance order ----------------
__global__ __launch_bounds__(256) void kloss(const float* __restrict__ expchunk,
                                             int rowBase,
                                             const float* __restrict__ slab_g,
                                             const int* __restrict__ perm_g,
                                             const int* __restrict__ pos_g,
                                             float* __restrict__ part_logd) {
  const int i = rowBase + blockIdx.x;
  const float* row = expchunk + (size_t)blockIdx.x * MM;
  __shared__ float P[PADI(MM) + 1];
  __shared__ __align__(16) float slab[MM];
  __shared__ float wsum[4];
  __shared__ float red[4];
  const int tid = threadIdx.x;
  const int lane = tid & 63, wid = tid >> 6;
  const int m0 = tid * 16;

  for (int d = 0; d < 2; ++d) {
    __syncthreads();
    for (int q = tid; q < MM / 4; q += 256)
      ((float4*)slab)[q] = ((const float4*)(slab_g + (size_t)d * MM))[q];

    const int pi = pos_g[d * MM + i];

    // gather exp_sims into sorted order (registers)
    float g[16];
    {
      const int4* pm4 = (const int4*)(perm_g + d * MM + m0);
      int idx[16];
#pragma unroll
      for (int q = 0; q < 4; ++q) {
        int4 p4 = pm4[q];
        idx[4 * q + 0] = p4.x; idx[4 * q + 1] = p4.y;
        idx[4 * q + 2] = p4.z; idx[4 * q + 3] = p4.w;
      }
#pragma unroll
      for (int u = 0; u < 16; ++u) g[u] = row[idx[u]];
    }
    float ls = 0.f;
#pragma unroll
    for (int u = 0; u < 16; ++u) ls += g[u];

    // wave-level inclusive scan of per-thread sums
    float v = ls;
#pragma unroll
    for (int s = 1; s < 64; s <<= 1) {
      float t = __shfl_up(v, s, 64);
      if (lane >= s) v += t;
    }
    if (lane == 63) wsum[wid] = v;
    __syncthreads();
    float woff = 0.f;
#pragma unroll
    for (int q = 0; q < 4; ++q) woff += (q < wid) ? wsum[q] : 0.f;
    const float total = wsum[0] + wsum[1] + wsum[2] + wsum[3];
    float run = woff + (v - ls);
#pragma unroll
    for (int u = 0; u < 16; ++u) {
      P[PADI(m0 + u)] = run;
      run += g[u];
    }
    if (tid == 0) P[PADI(MM)] = total;
    __syncthreads();

    const float c = slab[pi];

    // merge-path diagonal partition
    const int nB2 = MM - 1 - pi;
    const int k0r = m0;
    int aLo = k0r - nB2; if (aLo < 0) aLo = 0;
    int aHi = (k0r < pi) ? k0r : pi;
    while (aLo < aHi) {
      const int mid = (aLo + aHi) >> 1;
      const float Aa = c - slab[pi - 1 - mid];
      const float Bb = slab[pi + k0r - mid] - c;
      if (Aa > Bb) aHi = mid; else aLo = mid + 1;
    }
    int Lp = pi - 1 - aLo;
    int Rp = pi + 1 + (k0r - aLo);

    // P chains: PL1=P[Lp+1], PL0=P[Lp]; PR0=P[Rp], PR1=P[Rp+1]
    float PL1 = P[PADI(Lp + 1)];
    float PL0 = P[PADI(max(Lp, 0))];
    float PR0 = P[PADI(min(Rp, MM))];
    float PR1 = P[PADI(min(Rp + 1, MM))];
    float CS = PR0 - PL1;  // consumed interval (Lp, Rp) incl. center
    float tL = (Lp >= 0) ? (c - slab[Lp]) : INFINITY;
    float tR = (Rp < MM) ? (slab[Rp] - c) : INFINITY;
    float sLn = slab[max(Lp - 1, 0)];
    float sRn = slab[min(Rp + 1, MM - 1)];
    float pLn = P[PADI(max(Lp - 1, 0))];
    float pRn = P[PADI(min(Rp + 2, MM))];
    float lastT = 0.0f, lastDenom = total;
    float mprod = 1.f;
    int esum = 0;
    const int cnt = (MM - 1 - k0r < 16) ? (MM - 1 - k0r) : 16;
    for (int step = 0; step < cnt; ++step) {
      const bool left = (tL <= tR);
      const float t = left ? tL : tR;
      const float dr = total - CS;
      const float denom = (t == lastT) ? lastDenom : dr;
      lastT = t; lastDenom = denom;
      int ex;
      const float mant = frexpf(fmaxf(denom, 1e-7f), &ex);
      mprod *= mant;
      esum += ex;
      const float gv = left ? (PL1 - PL0) : (PR1 - PR0);
      CS += gv;
      Lp -= left ? 1 : 0;
      Rp += left ? 0 : 1;
      PL1 = left ? PL0 : PL1;
      PL0 = left ? pLn : PL0;
      PR0 = left ? PR0 : PR1;
      PR1 = left ? PR1 : pRn;
      tL = left ? ((Lp >= 0) ? (c - sLn) : INFINITY) : tL;
      tR = left ? tR : ((Rp < MM) ? (sRn - c) : INFINITY);
      const int sIdx = left ? max(Lp - 1, 0) : min(Rp + 1, MM - 1);
      const int pIdx = left ? max(Lp - 1, 0) : min(Rp + 2, MM);
      const float sv = slab[sIdx];
      const float pv = P[PADI(pIdx)];
      sLn = left ? sv : sLn;
      sRn = left ? sRn : sv;
      pLn = left ? pv : pLn;
      pRn = left ? pRn : pv;
    }
    float acc = __logf(mprod) + (float)esum * 0.6931471805599453f;

    for (int s = 32; s; s >>= 1) acc += __shfl_down(acc, s, 64);
    __syncthreads();
    if ((tid & 63) == 0) red[tid >> 6] = acc;
    __syncthreads();
    if (tid == 0) part_logd[d * MM + i] = red[0] + red[1] + red[2] + red[3];
  }
}

// ---------------- two-stage final reduce (double) ----------------
__global__ __launch_bounds__(256) void kred1(const float* __restrict__ part_logd,
                                             const float* __restrict__ srow,
                                             double* __restrict__ red3) {
  const int tid = threadIdx.x;
  const int base = blockIdx.x * 64;
  double ss = 0.0, s0 = 0.0, s1 = 0.0;
  for (int q = tid; q < 64 * 128; q += 256)
    ss += (double)srow[(size_t)base * 128 + q];
  if (tid < 64) {
    s0 = (double)part_logd[base + tid];
    s1 = (double)part_logd[MM + base + tid];
  }
  for (int s = 32; s; s >>= 1) {
    s0 += __shfl_down(s0, s, 64);
    s1 += __shfl_down(s1, s, 64);
    ss += __shfl_down(ss, s, 64);
  }
  __shared__ double red[3][4];
  if ((tid & 63) == 0) {
    red[0][tid >> 6] = s0; red[1][tid >> 6] = s1; red[2][tid >> 6] = ss;
  }
  __syncthreads();
  if (tid == 0) {
    red3[blockIdx.x * 3 + 0] = red[0][0] + red[0][1] + red[0][2] + red[0][3];
    red3[blockIdx.x * 3 + 1] = red[1][0] + red[1][1] + red[1][2] + red[1][3];
    red3[blockIdx.x * 3 + 2] = red[2][0] + red[2][1] + red[2][2] + red[2][3];
  }
}

__global__ __launch_bounds__(64) void kred2(const double* __restrict__ red3,
                                            float* __restrict__ out) {
  const int t = threadIdx.x;
  double s0 = red3[t * 3 + 0], s1 = red3[t * 3 + 1], ss = red3[t * 3 + 2];
  for (int s = 32; s; s >>= 1) {
    s0 += __shfl_down(s0, s, 64);
    s1 += __shfl_down(s1, s, 64);
    ss += __shfl_down(ss, s, 64);
  }
  if (t == 0) {
    const double n = (double)MM * (double)(MM - 1);
    out[0] = (float)((s0 - ss) / n);
    out[1] = (float)((s1 - ss) / n);
  }
}

extern "C" void kernel_launch(void* const* d_in, const int* in_sizes, int n_in,
                              void* d_out, int out_size, void* d_ws, size_t ws_size,
                              hipStream_t stream) {
  const float* emb = (const float*)d_in[0];
  const float* labels = (const float*)d_in[1];
  float* out = (float*)d_out;
  char* ws = (char*)d_ws;

  size_t off = 0;
  auto alloc = [&](size_t bytes) {
    void* p = ws + off;
    off = (off + bytes + 255) & ~(size_t)255;
    return p;
  };
  __hip_bfloat16* nb = (__hip_bfloat16*)alloc((size_t)MM * KK * 2);
  float* slab = (float*)alloc((size_t)2 * MM * 4);
  int* perm = (int*)alloc((size_t)2 * MM * 4);
  int* pos = (int*)alloc((size_t)2 * MM * 4);
  int* rank = (int*)alloc((size_t)2 * MM * 4);
  float* part_logd = (float*)alloc((size_t)2 * MM * 4);
  float* srow = (float*)alloc((size_t)MM * 128 * 4);
  double* red3 = (double*)alloc((size_t)64 * 3 * 8);
  size_t fixed = off;

  size_t avail = (ws_size > fixed) ? (ws_size - fixed) : 0;
  long long cr = (long long)(avail / ((size_t)MM * 4));
  cr = (cr / 128) * 128;
  if (cr > MM) cr = MM;
  if (cr < 128) cr = 128;
  int chunk_rows = (int)cr;
  float* expchunk = (float*)(ws + fixed);

  knorm<<<MM, 256, 0, stream>>>(emb, nb);
  hipMemsetAsync(rank, 0, (size_t)2 * MM * 4, stream);
  krank<<<dim3(16, 16, 2), 256, 0, stream>>>(labels, rank);
  kscatter<<<32, 256, 0, stream>>>(labels, rank, slab, perm, pos);

  if (chunk_rows == MM) {
    kgemm_sym64<<<NB64 * (NB64 + 1) / 2, 256, 0, stream>>>(nb, expchunk, srow);
    kloss<<<MM, 256, 0, stream>>>(expchunk, 0, slab, perm, pos, part_logd);
  } else {
    hipMemsetAsync(srow, 0, (size_t)MM * 128 * 4, stream);
    for (int base = 0; base < MM; base += chunk_rows) {
      int rows = MM - base < chunk_rows ? MM - base : chunk_rows;
      kgemm<<<dim3(MM / 128, rows / 128), 256, 0, stream>>>(nb, base, expchunk, srow);
      kloss<<<rows, 256, 0, stream>>>(expchunk, base, slab, perm, pos, part_logd);
    }
  }
  kred1<<<64, 256, 0, stream>>>(part_logd, srow, red3);
  kred2<<<1, 64, 0, stream>>>(red3, out);
}